// Round 1
// baseline (8525.256 us; speedup 1.0000x reference)
//
#include <hip/hip_runtime.h>
#include <hip/hip_bf16.h>
#include <math.h>
#include <float.h>

#define E0 131072
#define NN 32768
#define NB 1024
#define NSIDE 994
#define ETOT (E0 + NN)

__device__ inline void atomicMaxF(float* addr, float val) {
  if (val >= 0.f) atomicMax((int*)addr, __float_as_int(val));
  else atomicMin((unsigned int*)addr, __float_as_uint(val));
}

__global__ void fill_f32(float* p, float v, int n) {
  int i = blockIdx.x * blockDim.x + threadIdx.x;
  if (i < n) p[i] = v;
}
__global__ void fill_i32(int* p, int v, int n) {
  int i = blockIdx.x * blockDim.x + threadIdx.x;
  if (i < n) p[i] = v;
}
__global__ void copy_i32(const int* s, int* d, int n) {
  int i = blockIdx.x * blockDim.x + threadIdx.x;
  if (i < n) d[i] = s[i];
}

// ---------------- CSR build over dst ----------------
__global__ void count_deg(const int* __restrict__ ei, int* deg) {
  int e = blockIdx.x * blockDim.x + threadIdx.x;
  if (e >= ETOT) return;
  int dst = (e < E0) ? ei[E0 + e] : (e - E0);
  atomicAdd(&deg[dst], 1);
}

__global__ void scan_deg(const int* __restrict__ deg, int* rowptr) {
  __shared__ int part[1024];
  int tid = threadIdx.x;
  const int chunk = NN / 1024; // 32
  int base = tid * chunk;
  int local[chunk];
  int sum = 0;
#pragma unroll
  for (int i = 0; i < chunk; ++i) { local[i] = sum; sum += deg[base + i]; }
  part[tid] = sum;
  __syncthreads();
  for (int off = 1; off < 1024; off <<= 1) {
    int t = (tid >= off) ? part[tid - off] : 0;
    __syncthreads();
    part[tid] += t;
    __syncthreads();
  }
  int offset = part[tid] - sum; // exclusive prefix of this chunk
#pragma unroll
  for (int i = 0; i < chunk; ++i) rowptr[base + i] = offset + local[i];
  if (tid == 1023) rowptr[NN] = offset + sum;
}

__global__ void fill_csr(const int* __restrict__ ei, int* cursor, int* csr) {
  int e = blockIdx.x * blockDim.x + threadIdx.x;
  if (e >= ETOT) return;
  int dst = (e < E0) ? ei[E0 + e] : (e - E0);
  int pos = atomicAdd(&cursor[dst], 1);
  csr[pos] = e;
}

// ---------------- fp32 GEMM: C = act(A[M,K] @ B[K,N] + bias) ----------------
// ACT: 0 none, 1 relu, 2 tanh, 3 abs(tanh)
template <int ACT>
__global__ __launch_bounds__(256) void gemm_f32(
    const float* __restrict__ A, const float* __restrict__ B,
    const float* __restrict__ bias, float* __restrict__ C,
    int M, int K, int N, int lda, int ldb, int ldc) {
  __shared__ float As[16][64];
  __shared__ float Bs[16][64];
  const int tid = threadIdx.x;
  const int tx = tid & 15, ty = tid >> 4;
  const int bm = blockIdx.y * 64, bn = blockIdx.x * 64;
  float acc[4][4] = {{0.f}};
  for (int k0 = 0; k0 < K; k0 += 16) {
#pragma unroll
    for (int t = 0; t < 4; ++t) {
      int idx = tid * 4 + t;
      int r = idx >> 4, c = idx & 15;
      float va = 0.f;
      if (bm + r < M && k0 + c < K) va = A[(size_t)(bm + r) * lda + (k0 + c)];
      As[c][r] = va;
      int rb = idx >> 6, cb = idx & 63;
      float vb = 0.f;
      if (k0 + rb < K && bn + cb < N) vb = B[(size_t)(k0 + rb) * ldb + (bn + cb)];
      Bs[rb][cb] = vb;
    }
    __syncthreads();
#pragma unroll
    for (int kk = 0; kk < 16; ++kk) {
      float4 a4 = *reinterpret_cast<const float4*>(&As[kk][ty * 4]);
      float4 b4 = *reinterpret_cast<const float4*>(&Bs[kk][tx * 4]);
      float a[4] = {a4.x, a4.y, a4.z, a4.w};
      float b[4] = {b4.x, b4.y, b4.z, b4.w};
#pragma unroll
      for (int i = 0; i < 4; ++i)
#pragma unroll
        for (int j = 0; j < 4; ++j) acc[i][j] = fmaf(a[i], b[j], acc[i][j]);
    }
    __syncthreads();
  }
#pragma unroll
  for (int i = 0; i < 4; ++i) {
    int r = bm + ty * 4 + i;
    if (r >= M) continue;
#pragma unroll
    for (int j = 0; j < 4; ++j) {
      int cc = bn + tx * 4 + j;
      if (cc >= N) continue;
      float v = acc[i][j];
      if (bias) v += bias[cc];
      if (ACT == 1) v = v > 0.f ? v : 0.f;
      else if (ACT == 2) v = tanhf(v);
      else if (ACT == 3) v = fabsf(tanhf(v));
      C[(size_t)r * ldc + cc] = v;
    }
  }
}

// ---------------- GAT pieces ----------------
__global__ void gat_scores(const float* __restrict__ hlin,
                           const float* __restrict__ a_s, const float* __restrict__ a_d,
                           float* __restrict__ als, float* __restrict__ ald,
                           int H, int C, int tot) {
  int idx = blockIdx.x * blockDim.x + threadIdx.x;
  if (idx >= tot) return;
  int n = idx / H, h = idx - n * H;
  const float* base = hlin + (size_t)n * H * C + (size_t)h * C;
  const float* as = a_s + h * C;
  const float* ad = a_d + h * C;
  float ss = 0.f, sd = 0.f;
  for (int c = 0; c < C; ++c) {
    float v = base[c];
    ss = fmaf(v, as[c], ss);
    sd = fmaf(v, ad[c], sd);
  }
  als[idx] = ss;
  ald[idx] = sd;
}

__global__ void edge_max(const int* __restrict__ ei, const float* __restrict__ als,
                         const float* __restrict__ ald, float* __restrict__ eb,
                         float* mb, int H, int tot) {
  int idx = blockIdx.x * blockDim.x + threadIdx.x;
  if (idx >= tot) return;
  int e = idx / H, h = idx - e * H;
  int src, dst;
  if (e < E0) { src = ei[e]; dst = ei[E0 + e]; } else { src = dst = e - E0; }
  float v = als[src * H + h] + ald[dst * H + h];
  v = (v >= 0.f) ? v : 0.2f * v;  // leaky_relu 0.2
  eb[idx] = v;
  atomicMaxF(&mb[dst * H + h], v);
}

__global__ void edge_exp(const int* __restrict__ ei, float* __restrict__ eb,
                         const float* __restrict__ mb, float* sb, int H, int tot) {
  int idx = blockIdx.x * blockDim.x + threadIdx.x;
  if (idx >= tot) return;
  int e = idx / H, h = idx - e * H;
  int dst = (e < E0) ? ei[E0 + e] : (e - E0);
  float p = expf(eb[idx] - mb[dst * H + h]);
  eb[idx] = p;
  atomicAdd(&sb[dst * H + h], p);
}

__global__ __launch_bounds__(256) void gat_aggregate(
    const int* __restrict__ rowptr, const int* __restrict__ csr,
    const int* __restrict__ ei, const float* __restrict__ eb,
    const float* __restrict__ sb, const float* __restrict__ hlin,
    const float* __restrict__ bias, float* __restrict__ out, int H, int C) {
  int n = blockIdx.x;
  int F = H * C;
  int start = rowptr[n], end = rowptr[n + 1];
  for (int c = threadIdx.x; c < F; c += blockDim.x) {
    int h = c / C;
    float inv_s = 1.f / sb[n * H + h];
    float acc = 0.f;
    for (int k = start; k < end; ++k) {
      int eid = csr[k];
      int src = (eid < E0) ? ei[eid] : (eid - E0);
      float alpha = eb[(size_t)eid * H + h] * inv_s;
      acc = fmaf(alpha, hlin[(size_t)src * F + c], acc);
    }
    float val = acc + bias[c];
    out[(size_t)n * F + c] = val > 0.f ? val : 0.f;  // relu
  }
}

__global__ void pool_scatter(const float* __restrict__ h, const int* __restrict__ batch,
                             float* xg, int F, int tot) {
  int idx = blockIdx.x * blockDim.x + threadIdx.x;
  if (idx >= tot) return;
  int n = idx / F, f = idx - n * F;
  atomicMaxF(&xg[batch[n] * F + f], h[idx]);
}

// rows of 64, one wave per row
__global__ void rownorm(const float* __restrict__ in, float* __restrict__ outp) {
  int r = blockIdx.x, lane = threadIdx.x;
  float v = in[r * 64 + lane];
  float ss = v * v;
#pragma unroll
  for (int off = 1; off < 64; off <<= 1) ss += __shfl_xor(ss, off);
  float nrm = fmaxf(sqrtf(ss), 1e-12f);
  outp[r * 64 + lane] = v / nrm;
}

// C[M,N] = 5 * A[M,64] @ B[N,64]^T
__global__ __launch_bounds__(256) void freq_k(const float* __restrict__ dn,
                                              const float* __restrict__ sn,
                                              float* __restrict__ C, int M, int N) {
  __shared__ float As[16][64];
  __shared__ float Bs[16][65];
  int tid = threadIdx.x;
  int tx = tid & 15, ty = tid >> 4;
  int bi = blockIdx.y * 16, bj = blockIdx.x * 16;
#pragma unroll
  for (int t = 0; t < 4; ++t) {
    int idx = tid * 4 + t;
    int r = idx >> 6, c = idx & 63;
    As[r][c] = (bi + r < M) ? dn[(bi + r) * 64 + c] : 0.f;
    Bs[r][c] = (bj + r < N) ? sn[(bj + r) * 64 + c] : 0.f;
  }
  __syncthreads();
  float acc = 0.f;
#pragma unroll
  for (int k = 0; k < 64; ++k) acc = fmaf(As[ty][k], Bs[tx][k], acc);
  if (bi + ty < M && bj + tx < N) C[(size_t)(bi + ty) * N + (bj + tx)] = 5.f * acc;
}

// ---------------- launch ----------------
extern "C" void kernel_launch(void* const* d_in, const int* in_sizes, int n_in,
                              void* d_out, int out_size, void* d_ws, size_t ws_size,
                              hipStream_t stream) {
  const float* x = (const float*)d_in[0];
  const int* ei = (const int*)d_in[1];
  const int* batch = (const int*)d_in[2];
  const float* w = (const float*)d_in[3];
  const float* z = (const float*)d_in[4];
  const float* v = (const float*)d_in[5];
  const float* side = (const float*)d_in[6];
  const float* gW[4] = {(const float*)d_in[7], (const float*)d_in[11],
                        (const float*)d_in[15], (const float*)d_in[19]};
  const float* gas[4] = {(const float*)d_in[8], (const float*)d_in[12],
                         (const float*)d_in[16], (const float*)d_in[20]};
  const float* gad[4] = {(const float*)d_in[9], (const float*)d_in[13],
                         (const float*)d_in[17], (const float*)d_in[21]};
  const float* gb[4] = {(const float*)d_in[10], (const float*)d_in[14],
                        (const float*)d_in[18], (const float*)d_in[22]};
  const float* x5_W = (const float*)d_in[23]; const float* x5_b = (const float*)d_in[24];
  const float* x6_W = (const float*)d_in[25]; const float* x6_b = (const float*)d_in[26];
  const float* w1_W = (const float*)d_in[27]; const float* w1_b = (const float*)d_in[28];
  const float* w2_W = (const float*)d_in[29]; const float* w2_b = (const float*)d_in[30];
  const float* z1_W = (const float*)d_in[31]; const float* z1_b = (const float*)d_in[32];
  const float* z2_W = (const float*)d_in[33]; const float* z2_b = (const float*)d_in[34];
  const float* v1_W = (const float*)d_in[35]; const float* v1_b = (const float*)d_in[36];
  const float* v2_W = (const float*)d_in[37]; const float* v2_b = (const float*)d_in[38];
  const float* agg_W = (const float*)d_in[39]; const float* agg_b = (const float*)d_in[40];
  const float* col_W = (const float*)d_in[41]; const float* col_b = (const float*)d_in[42];
  const float* s1_W = (const float*)d_in[43]; const float* s1_b = (const float*)d_in[44];
  const float* s2_W = (const float*)d_in[45]; const float* s2_b = (const float*)d_in[46];

  float* ws = (float*)d_ws;
  size_t off = 0;
  auto alloc = [&](size_t n) { float* p = ws + off; off += n; return p; };
  float* BUF0 = alloc((size_t)NN * 1024);
  float* BUF1 = alloc((size_t)NN * 1024);
  float* EB = alloc((size_t)ETOT * 8);
  float* ALS = alloc((size_t)NN * 8);
  float* ALD = alloc((size_t)NN * 8);
  float* MB = alloc((size_t)NN * 8);
  float* SB = alloc((size_t)NN * 8);
  float* ZMID = alloc((size_t)NB * 1600);
  float* WMID = alloc((size_t)NB * 750);
  float* VMID = alloc((size_t)NB * 256);
  float* XG = alloc((size_t)NB * 128);
  float* X5O = alloc((size_t)NB * 64);
  float* CAT192 = alloc((size_t)NB * 192);
  float* CAT128 = alloc((size_t)NB * 128);
  float* DRUG = alloc((size_t)NB * 64);
  float* SEMID = alloc((size_t)NSIDE * 64);
  float* SE = alloc((size_t)NSIDE * 64);
  int* ibase = (int*)(ws + off);
  int* DEG = ibase;
  int* ROWPTR = DEG + NN;
  int* CURSOR = ROWPTR + NN + 1;
  int* CSR = CURSOR + NN;

  auto launch_gemm = [&](int act, const float* A, const float* B, const float* bias,
                         float* C, int M, int K, int N, int lda, int ldb, int ldc) {
    dim3 g((N + 63) / 64, (M + 63) / 64);
    switch (act) {
      case 0: hipLaunchKernelGGL((gemm_f32<0>), g, dim3(256), 0, stream, A, B, bias, C, M, K, N, lda, ldb, ldc); break;
      case 1: hipLaunchKernelGGL((gemm_f32<1>), g, dim3(256), 0, stream, A, B, bias, C, M, K, N, lda, ldb, ldc); break;
      case 2: hipLaunchKernelGGL((gemm_f32<2>), g, dim3(256), 0, stream, A, B, bias, C, M, K, N, lda, ldb, ldc); break;
      case 3: hipLaunchKernelGGL((gemm_f32<3>), g, dim3(256), 0, stream, A, B, bias, C, M, K, N, lda, ldb, ldc); break;
    }
  };

  // CSR build (dst-sorted incoming edge lists)
  hipLaunchKernelGGL(fill_i32, dim3((NN + 255) / 256), dim3(256), 0, stream, DEG, 0, NN);
  hipLaunchKernelGGL(count_deg, dim3((ETOT + 255) / 256), dim3(256), 0, stream, ei, DEG);
  hipLaunchKernelGGL(scan_deg, dim3(1), dim3(1024), 0, stream, DEG, ROWPTR);
  hipLaunchKernelGGL(copy_i32, dim3((NN + 255) / 256), dim3(256), 0, stream, ROWPTR, CURSOR, NN);
  hipLaunchKernelGGL(fill_csr, dim3((ETOT + 255) / 256), dim3(256), 0, stream, ei, CURSOR, CSR);

  // GAT layers
  const int Hs[4] = {8, 8, 8, 1};
  const int Cs[4] = {96, 128, 128, 128};
  const float* hin = x;
  int Fin = 109;
  for (int l = 0; l < 4; ++l) {
    int H = Hs[l], C = Cs[l], F = H * C;
    launch_gemm(0, hin, gW[l], nullptr, BUF0, NN, Fin, F, Fin, F, F);
    int totNH = NN * H;
    hipLaunchKernelGGL(gat_scores, dim3((totNH + 255) / 256), dim3(256), 0, stream,
                       BUF0, gas[l], gad[l], ALS, ALD, H, C, totNH);
    hipLaunchKernelGGL(fill_f32, dim3((totNH + 255) / 256), dim3(256), 0, stream, MB, -INFINITY, totNH);
    hipLaunchKernelGGL(fill_f32, dim3((totNH + 255) / 256), dim3(256), 0, stream, SB, 0.f, totNH);
    int totEH = ETOT * H;
    hipLaunchKernelGGL(edge_max, dim3((totEH + 255) / 256), dim3(256), 0, stream, ei, ALS, ALD, EB, MB, H, totEH);
    hipLaunchKernelGGL(edge_exp, dim3((totEH + 255) / 256), dim3(256), 0, stream, ei, EB, MB, SB, H, totEH);
    int bdim = (F >= 256) ? 256 : F;
    hipLaunchKernelGGL(gat_aggregate, dim3(NN), dim3(bdim), 0, stream,
                       ROWPTR, CSR, ei, EB, SB, BUF0, gb[l], BUF1, H, C);
    hin = BUF1;
    Fin = F;
  }

  // global max pool
  hipLaunchKernelGGL(fill_f32, dim3((NB * 128 + 255) / 256), dim3(256), 0, stream, XG, -FLT_MAX, NB * 128);
  hipLaunchKernelGGL(pool_scatter, dim3((NN * 128 + 255) / 256), dim3(256), 0, stream, BUF1, batch, XG, 128, NN * 128);

  // MLP chains
  launch_gemm(1, XG, x5_W, x5_b, X5O, NB, 128, 64, 128, 64, 64);
  launch_gemm(1, X5O, x6_W, x6_b, CAT192 + 0, NB, 64, 64, 64, 64, 192);
  launch_gemm(1, w, w1_W, w1_b, WMID, NB, 750, 750, 750, 750, 750);
  launch_gemm(1, WMID, w2_W, w2_b, CAT192 + 64, NB, 750, 64, 750, 64, 192);
  launch_gemm(1, z, z1_W, z1_b, ZMID, NB, 19127, 1600, 19127, 1600, 1600);
  launch_gemm(1, ZMID, z2_W, z2_b, CAT192 + 128, NB, 1600, 64, 1600, 64, 192);
  launch_gemm(1, v, v1_W, v1_b, VMID, NB, 1024, 256, 1024, 256, 256);
  launch_gemm(1, VMID, v2_W, v2_b, CAT128 + 64, NB, 256, 64, 256, 64, 128);
  launch_gemm(0, CAT192, agg_W, agg_b, CAT128 + 0, NB, 192, 64, 192, 64, 128);
  launch_gemm(3, CAT128, col_W, col_b, DRUG, NB, 128, 64, 128, 64, 64);
  launch_gemm(1, side, s1_W, s1_b, SEMID, NSIDE, 1050, 64, 1050, 64, 64);
  launch_gemm(2, SEMID, s2_W, s2_b, SE, NSIDE, 64, 64, 64, 64, 64);

  // normalize + similarity
  float* outp = (float*)d_out;
  float* DN = outp + (size_t)NB * NSIDE;
  float* SN = DN + (size_t)NB * 64;
  hipLaunchKernelGGL(rownorm, dim3(NB), dim3(64), 0, stream, DRUG, DN);
  hipLaunchKernelGGL(rownorm, dim3(NSIDE), dim3(64), 0, stream, SE, SN);
  hipLaunchKernelGGL(freq_k, dim3((NSIDE + 15) / 16, (NB + 15) / 16), dim3(256), 0, stream,
                     DN, SN, outp, NB, NSIDE);
}

// Round 2
// 2562.845 us; speedup vs baseline: 3.3265x; 3.3265x over previous
//
#include <hip/hip_runtime.h>
#include <math.h>
#include <float.h>

#define E0 131072
#define NN 32768
#define NB 1024
#define NSIDE 994
#define ETOT (E0 + NN)

typedef short bf16x8 __attribute__((ext_vector_type(8)));
typedef unsigned short ushort8 __attribute__((ext_vector_type(8)));
typedef float f32x4 __attribute__((ext_vector_type(4)));

__device__ inline float b2f(unsigned short u) { return __uint_as_float(((unsigned)u) << 16); }
__device__ inline unsigned short f2b(float f) {
  unsigned u = __float_as_uint(f);
  return (unsigned short)((u + 0x7fffu + ((u >> 16) & 1u)) >> 16);
}

__device__ inline void gload_lds16(const void* g, void* l) {
  __builtin_amdgcn_global_load_lds(
      (const __attribute__((address_space(1))) unsigned int*)g,
      (__attribute__((address_space(3))) unsigned int*)l, 16, 0, 0);
}

__device__ inline void atomicMaxF(float* addr, float val) {
  if (val >= 0.f) atomicMax((int*)addr, __float_as_int(val));
  else atomicMin((unsigned int*)addr, __float_as_uint(val));
}

__global__ void fill_f32(float* p, float v, int n) {
  int i = blockIdx.x * blockDim.x + threadIdx.x;
  if (i < n) p[i] = v;
}
__global__ void fill_i32(int* p, int v, int n) {
  int i = blockIdx.x * blockDim.x + threadIdx.x;
  if (i < n) p[i] = v;
}
__global__ void copy_i32(const int* s, int* d, int n) {
  int i = blockIdx.x * blockDim.x + threadIdx.x;
  if (i < n) d[i] = s[i];
}

// ---------------- fp32 -> bf16 conversion with column padding ----------------
__global__ void conv_pad(const float* __restrict__ in, unsigned short* __restrict__ out,
                         int rows, int C, int Cp) {
  size_t idx = (size_t)blockIdx.x * blockDim.x + threadIdx.x;
  size_t tot = (size_t)rows * Cp;
  if (idx >= tot) return;
  int r = (int)(idx / Cp), c = (int)(idx % Cp);
  out[idx] = (c < C) ? f2b(in[(size_t)r * C + c]) : (unsigned short)0;
}

// W [K][N] f32  ->  WT [N][Kp] bf16 (zero-pad k in [K,Kp))
__global__ __launch_bounds__(256) void transpose_w(const float* __restrict__ W,
                                                   unsigned short* __restrict__ WT,
                                                   int K, int N, int Kp) {
  __shared__ float t[32][33];
  int k0 = blockIdx.y * 32, n0 = blockIdx.x * 32;
  int tx = threadIdx.x & 31, ty = threadIdx.x >> 5;  // ty 0..7
  for (int r = ty; r < 32; r += 8) {
    int k = k0 + r, n = n0 + tx;
    t[r][tx] = (k < K && n < N) ? W[(size_t)k * N + n] : 0.f;
  }
  __syncthreads();
  for (int r = ty; r < 32; r += 8) {
    int n = n0 + r, k = k0 + tx;
    if (n < N && k < Kp) WT[(size_t)n * Kp + k] = f2b(t[tx][r]);
  }
}

// ---------------- CSR build over dst ----------------
__global__ void count_deg(const int* __restrict__ ei, int* deg) {
  int e = blockIdx.x * blockDim.x + threadIdx.x;
  if (e >= ETOT) return;
  int dst = (e < E0) ? ei[E0 + e] : (e - E0);
  atomicAdd(&deg[dst], 1);
}

__global__ void scan_deg(const int* __restrict__ deg, int* rowptr) {
  __shared__ int part[1024];
  int tid = threadIdx.x;
  const int chunk = NN / 1024;  // 32
  int base = tid * chunk;
  int local[chunk];
  int sum = 0;
#pragma unroll
  for (int i = 0; i < chunk; ++i) { local[i] = sum; sum += deg[base + i]; }
  part[tid] = sum;
  __syncthreads();
  for (int off = 1; off < 1024; off <<= 1) {
    int t = (tid >= off) ? part[tid - off] : 0;
    __syncthreads();
    part[tid] += t;
    __syncthreads();
  }
  int offset = part[tid] - sum;
#pragma unroll
  for (int i = 0; i < chunk; ++i) rowptr[base + i] = offset + local[i];
  if (tid == 1023) rowptr[NN] = offset + sum;
}

__global__ void fill_csr(const int* __restrict__ ei, int* cursor, int* csr) {
  int e = blockIdx.x * blockDim.x + threadIdx.x;
  if (e >= ETOT) return;
  int dst = (e < E0) ? ei[E0 + e] : (e - E0);
  int pos = atomicAdd(&cursor[dst], 1);
  csr[pos] = e;
}

// ---------------- bf16 MFMA GEMM: C = act(A[M,K] @ BT[N,K]^T + bias) ----------------
// 128x128 tile, BK=32, 4 waves (2x2), per-wave 64x64 via 4x4 of 16x16x32 MFMA.
// M % 128 == 0, Npad % 128 == 0, K % 32 == 0, lda/ldb % 8 == 0. Col store guarded by Nreal.
// ACT: 0 none, 1 relu.  OBF: 1 -> bf16 out, 0 -> f32 out.
template <int ACT, int OBF>
__global__ __launch_bounds__(256) void gemm_mfma(
    const unsigned short* __restrict__ A, const unsigned short* __restrict__ BT,
    const float* __restrict__ bias, void* __restrict__ Cp,
    int Nreal, int K, int lda, int ldb, int ldc) {
  __shared__ unsigned short As[128 * 32];
  __shared__ unsigned short Bs[128 * 32];
  const int tid = threadIdx.x;
  const int wv = tid >> 6, lane = tid & 63;
  const int sr = lane >> 2, sk = (lane & 3) * 8;  // staging: row-in-chunk, k-offset
  const int r16 = lane & 15, kq = lane >> 4;
  const int wr = wv >> 1, wc = wv & 1;
  const int bm = blockIdx.y * 128, bn = blockIdx.x * 128;
  f32x4 acc[4][4];
#pragma unroll
  for (int i = 0; i < 4; ++i)
#pragma unroll
    for (int j = 0; j < 4; ++j) acc[i][j] = (f32x4){0.f, 0.f, 0.f, 0.f};

  const unsigned short* Abase = A + (size_t)bm * lda;
  const unsigned short* Bbase = BT + (size_t)bn * ldb;
  for (int k0 = 0; k0 < K; k0 += 32) {
    // stage A-tile [128][32] and B-tile [128][32]; LDS dest wave-uniform, global per-lane
    gload_lds16(Abase + (size_t)(wv * 16 + sr) * lda + k0 + sk, &As[wv * 512]);
    gload_lds16(Abase + (size_t)(64 + wv * 16 + sr) * lda + k0 + sk, &As[2048 + wv * 512]);
    gload_lds16(Bbase + (size_t)(wv * 16 + sr) * ldb + k0 + sk, &Bs[wv * 512]);
    gload_lds16(Bbase + (size_t)(64 + wv * 16 + sr) * ldb + k0 + sk, &Bs[2048 + wv * 512]);
    __syncthreads();
    bf16x8 af[4], bfr[4];
#pragma unroll
    for (int i = 0; i < 4; ++i)
      af[i] = *(const bf16x8*)&As[(wr * 64 + i * 16 + r16) * 32 + kq * 8];
#pragma unroll
    for (int j = 0; j < 4; ++j)
      bfr[j] = *(const bf16x8*)&Bs[(wc * 64 + j * 16 + r16) * 32 + kq * 8];
#pragma unroll
    for (int i = 0; i < 4; ++i)
#pragma unroll
      for (int j = 0; j < 4; ++j)
        acc[i][j] = __builtin_amdgcn_mfma_f32_16x16x32_bf16(af[i], bfr[j], acc[i][j], 0, 0, 0);
    __syncthreads();
  }
#pragma unroll
  for (int i = 0; i < 4; ++i) {
    int row = bm + wr * 64 + i * 16 + kq * 4;
#pragma unroll
    for (int j = 0; j < 4; ++j) {
      int col = bn + wc * 64 + j * 16 + r16;
      if (col >= Nreal) continue;
      float bv = bias ? bias[col] : 0.f;
#pragma unroll
      for (int r = 0; r < 4; ++r) {
        float v = acc[i][j][r] + bv;
        if (ACT == 1) v = v > 0.f ? v : 0.f;
        if (OBF) ((unsigned short*)Cp)[(size_t)(row + r) * ldc + col] = f2b(v);
        else ((float*)Cp)[(size_t)(row + r) * ldc + col] = v;
      }
    }
  }
}

// ---------------- fp32 GEMM for small layers ----------------
template <int ACT>
__global__ __launch_bounds__(256) void gemm_f32(
    const float* __restrict__ A, const float* __restrict__ B,
    const float* __restrict__ bias, float* __restrict__ C,
    int M, int K, int N, int lda, int ldb, int ldc) {
  __shared__ float As[16][64];
  __shared__ float Bs[16][64];
  const int tid = threadIdx.x;
  const int tx = tid & 15, ty = tid >> 4;
  const int bm = blockIdx.y * 64, bn = blockIdx.x * 64;
  float acc[4][4] = {{0.f}};
  for (int k0 = 0; k0 < K; k0 += 16) {
#pragma unroll
    for (int t = 0; t < 4; ++t) {
      int idx = tid * 4 + t;
      int r = idx >> 4, c = idx & 15;
      float va = 0.f;
      if (bm + r < M && k0 + c < K) va = A[(size_t)(bm + r) * lda + (k0 + c)];
      As[c][r] = va;
      int rb = idx >> 6, cb = idx & 63;
      float vb = 0.f;
      if (k0 + rb < K && bn + cb < N) vb = B[(size_t)(k0 + rb) * ldb + (bn + cb)];
      Bs[rb][cb] = vb;
    }
    __syncthreads();
#pragma unroll
    for (int kk = 0; kk < 16; ++kk) {
      float4 a4 = *reinterpret_cast<const float4*>(&As[kk][ty * 4]);
      float4 b4 = *reinterpret_cast<const float4*>(&Bs[kk][tx * 4]);
      float a[4] = {a4.x, a4.y, a4.z, a4.w};
      float b[4] = {b4.x, b4.y, b4.z, b4.w};
#pragma unroll
      for (int i = 0; i < 4; ++i)
#pragma unroll
        for (int j = 0; j < 4; ++j) acc[i][j] = fmaf(a[i], b[j], acc[i][j]);
    }
    __syncthreads();
  }
#pragma unroll
  for (int i = 0; i < 4; ++i) {
    int r = bm + ty * 4 + i;
    if (r >= M) continue;
#pragma unroll
    for (int j = 0; j < 4; ++j) {
      int cc = bn + tx * 4 + j;
      if (cc >= N) continue;
      float v = acc[i][j];
      if (bias) v += bias[cc];
      if (ACT == 1) v = v > 0.f ? v : 0.f;
      else if (ACT == 2) v = tanhf(v);
      else if (ACT == 3) v = fabsf(tanhf(v));
      C[(size_t)r * ldc + cc] = v;
    }
  }
}

// ---------------- GAT pieces (bf16 features) ----------------
__global__ void gat_scores_bf(const unsigned short* __restrict__ hlin,
                              const float* __restrict__ a_s, const float* __restrict__ a_d,
                              float* __restrict__ als, float* __restrict__ ald,
                              int H, int C, int tot) {
  int idx = blockIdx.x * blockDim.x + threadIdx.x;
  if (idx >= tot) return;
  int n = idx / H, h = idx - n * H;
  const unsigned short* base = hlin + (size_t)n * H * C + (size_t)h * C;
  const float* as = a_s + h * C;
  const float* ad = a_d + h * C;
  float ss = 0.f, sd = 0.f;
  for (int c = 0; c < C; c += 8) {
    ushort8 v = *(const ushort8*)(base + c);
#pragma unroll
    for (int t = 0; t < 8; ++t) {
      float f = b2f(v[t]);
      ss = fmaf(f, as[c + t], ss);
      sd = fmaf(f, ad[c + t], sd);
    }
  }
  als[idx] = ss;
  ald[idx] = sd;
}

__global__ void edge_max(const int* __restrict__ ei, const float* __restrict__ als,
                         const float* __restrict__ ald, float* __restrict__ eb,
                         float* mb, int H, int tot) {
  int idx = blockIdx.x * blockDim.x + threadIdx.x;
  if (idx >= tot) return;
  int e = idx / H, h = idx - e * H;
  int src, dst;
  if (e < E0) { src = ei[e]; dst = ei[E0 + e]; } else { src = dst = e - E0; }
  float v = als[src * H + h] + ald[dst * H + h];
  v = (v >= 0.f) ? v : 0.2f * v;  // leaky_relu 0.2
  eb[idx] = v;
  atomicMaxF(&mb[dst * H + h], v);
}

__global__ void edge_exp(const int* __restrict__ ei, float* __restrict__ eb,
                         const float* __restrict__ mb, float* sb, int H, int tot) {
  int idx = blockIdx.x * blockDim.x + threadIdx.x;
  if (idx >= tot) return;
  int e = idx / H, h = idx - e * H;
  int dst = (e < E0) ? ei[E0 + e] : (e - E0);
  float p = expf(eb[idx] - mb[dst * H + h]);
  eb[idx] = p;
  atomicAdd(&sb[dst * H + h], p);
}

__global__ __launch_bounds__(256) void gat_aggregate_bf(
    const int* __restrict__ rowptr, const int* __restrict__ csr,
    const int* __restrict__ ei, const float* __restrict__ eb,
    const float* __restrict__ sb, const unsigned short* __restrict__ hlin,
    const float* __restrict__ bias, unsigned short* __restrict__ out, int H, int C) {
  int n = blockIdx.x;
  int F = H * C;
  int start = rowptr[n], end = rowptr[n + 1];
  for (int c = threadIdx.x; c < F; c += blockDim.x) {
    int h = c / C;
    float inv_s = 1.f / sb[n * H + h];
    float acc = 0.f;
    for (int k = start; k < end; ++k) {
      int eid = csr[k];
      int src = (eid < E0) ? ei[eid] : (eid - E0);
      float p = eb[(size_t)eid * H + h];
      acc = fmaf(p, b2f(hlin[(size_t)src * F + c]), acc);
    }
    float val = acc * inv_s + bias[c];
    out[(size_t)n * F + c] = f2b(val > 0.f ? val : 0.f);  // relu
  }
}

__global__ void pool_scatter_bf(const unsigned short* __restrict__ h,
                                const int* __restrict__ batch, float* xg, int F, int tot) {
  int idx = blockIdx.x * blockDim.x + threadIdx.x;
  if (idx >= tot) return;
  int n = idx / F, f = idx - n * F;
  atomicMaxF(&xg[batch[n] * F + f], b2f(h[idx]));
}

// rows of 64, one wave per row
__global__ void rownorm(const float* __restrict__ in, float* __restrict__ outp) {
  int r = blockIdx.x, lane = threadIdx.x;
  float v = in[r * 64 + lane];
  float ss = v * v;
#pragma unroll
  for (int off = 1; off < 64; off <<= 1) ss += __shfl_xor(ss, off);
  float nrm = fmaxf(sqrtf(ss), 1e-12f);
  outp[r * 64 + lane] = v / nrm;
}

// C[M,N] = 5 * A[M,64] @ B[N,64]^T
__global__ __launch_bounds__(256) void freq_k(const float* __restrict__ dn,
                                              const float* __restrict__ sn,
                                              float* __restrict__ C, int M, int N) {
  __shared__ float As[16][64];
  __shared__ float Bs[16][65];
  int tid = threadIdx.x;
  int tx = tid & 15, ty = tid >> 4;
  int bi = blockIdx.y * 16, bj = blockIdx.x * 16;
#pragma unroll
  for (int t = 0; t < 4; ++t) {
    int idx = tid * 4 + t;
    int r = idx >> 6, c = idx & 63;
    As[r][c] = (bi + r < M) ? dn[(bi + r) * 64 + c] : 0.f;
    Bs[r][c] = (bj + r < N) ? sn[(bj + r) * 64 + c] : 0.f;
  }
  __syncthreads();
  float acc = 0.f;
#pragma unroll
  for (int k = 0; k < 64; ++k) acc = fmaf(As[ty][k], Bs[tx][k], acc);
  if (bi + ty < M && bj + tx < N) C[(size_t)(bi + ty) * N + (bj + tx)] = 5.f * acc;
}

// ---------------- launch ----------------
extern "C" void kernel_launch(void* const* d_in, const int* in_sizes, int n_in,
                              void* d_out, int out_size, void* d_ws, size_t ws_size,
                              hipStream_t stream) {
  const float* x = (const float*)d_in[0];
  const int* ei = (const int*)d_in[1];
  const int* batch = (const int*)d_in[2];
  const float* w = (const float*)d_in[3];
  const float* z = (const float*)d_in[4];
  const float* v = (const float*)d_in[5];
  const float* side = (const float*)d_in[6];
  const float* gW[4] = {(const float*)d_in[7], (const float*)d_in[11],
                        (const float*)d_in[15], (const float*)d_in[19]};
  const float* gas[4] = {(const float*)d_in[8], (const float*)d_in[12],
                         (const float*)d_in[16], (const float*)d_in[20]};
  const float* gad[4] = {(const float*)d_in[9], (const float*)d_in[13],
                         (const float*)d_in[17], (const float*)d_in[21]};
  const float* gb[4] = {(const float*)d_in[10], (const float*)d_in[14],
                        (const float*)d_in[18], (const float*)d_in[22]};
  const float* x5_W = (const float*)d_in[23]; const float* x5_b = (const float*)d_in[24];
  const float* x6_W = (const float*)d_in[25]; const float* x6_b = (const float*)d_in[26];
  const float* w1_W = (const float*)d_in[27]; const float* w1_b = (const float*)d_in[28];
  const float* w2_W = (const float*)d_in[29]; const float* w2_b = (const float*)d_in[30];
  const float* z1_W = (const float*)d_in[31]; const float* z1_b = (const float*)d_in[32];
  const float* z2_W = (const float*)d_in[33]; const float* z2_b = (const float*)d_in[34];
  const float* v1_W = (const float*)d_in[35]; const float* v1_b = (const float*)d_in[36];
  const float* v2_W = (const float*)d_in[37]; const float* v2_b = (const float*)d_in[38];
  const float* agg_W = (const float*)d_in[39]; const float* agg_b = (const float*)d_in[40];
  const float* col_W = (const float*)d_in[41]; const float* col_b = (const float*)d_in[42];
  const float* s1_W = (const float*)d_in[43]; const float* s1_b = (const float*)d_in[44];
  const float* s2_W = (const float*)d_in[45]; const float* s2_b = (const float*)d_in[46];

  char* wsb = (char*)d_ws;
  size_t off = 0;
  auto alloc = [&](size_t bytes) {
    void* p = wsb + off;
    off = (off + bytes + 255) & ~(size_t)255;
    return p;
  };
  unsigned short* HLIN = (unsigned short*)alloc((size_t)NN * 1024 * 2);
  unsigned short* XB = (unsigned short*)alloc((size_t)NN * 1024 * 2);
  unsigned short* WT1 = (unsigned short*)alloc((size_t)768 * 128 * 2);
  unsigned short* WT2 = (unsigned short*)alloc((size_t)1024 * 768 * 2);
  unsigned short* WT3 = (unsigned short*)alloc((size_t)1024 * 1024 * 2);
  unsigned short* WT4 = (unsigned short*)alloc((size_t)128 * 1024 * 2);
  unsigned short* WTZ = (unsigned short*)alloc((size_t)1664 * 19136 * 2);
  unsigned short* ZA = (unsigned short*)alloc((size_t)1024 * 19136 * 2);
  float* ZMID = (float*)alloc((size_t)NB * 1664 * 4);
  float* EB = (float*)alloc((size_t)ETOT * 8 * 4);
  float* ALS = (float*)alloc((size_t)NN * 8 * 4);
  float* ALD = (float*)alloc((size_t)NN * 8 * 4);
  float* MBUF = (float*)alloc((size_t)NN * 8 * 4);
  float* SB = (float*)alloc((size_t)NN * 8 * 4);
  float* WMID = (float*)alloc((size_t)NB * 750 * 4);
  float* VMID = (float*)alloc((size_t)NB * 256 * 4);
  float* XG = (float*)alloc((size_t)NB * 128 * 4);
  float* X5O = (float*)alloc((size_t)NB * 64 * 4);
  float* CAT192 = (float*)alloc((size_t)NB * 192 * 4);
  float* CAT128 = (float*)alloc((size_t)NB * 128 * 4);
  float* DRUG = (float*)alloc((size_t)NB * 64 * 4);
  float* SEMID = (float*)alloc((size_t)NSIDE * 64 * 4);
  float* SE = (float*)alloc((size_t)NSIDE * 64 * 4);
  int* DEG = (int*)alloc((size_t)NN * 4);
  int* ROWPTR = (int*)alloc((size_t)(NN + 1) * 4);
  int* CURSOR = (int*)alloc((size_t)NN * 4);
  int* CSR = (int*)alloc((size_t)ETOT * 4);

  auto launch_gemm = [&](int act, const float* A, const float* B, const float* bias,
                         float* C, int M, int K, int N, int lda, int ldb, int ldc) {
    dim3 g((N + 63) / 64, (M + 63) / 64);
    switch (act) {
      case 0: hipLaunchKernelGGL((gemm_f32<0>), g, dim3(256), 0, stream, A, B, bias, C, M, K, N, lda, ldb, ldc); break;
      case 1: hipLaunchKernelGGL((gemm_f32<1>), g, dim3(256), 0, stream, A, B, bias, C, M, K, N, lda, ldb, ldc); break;
      case 2: hipLaunchKernelGGL((gemm_f32<2>), g, dim3(256), 0, stream, A, B, bias, C, M, K, N, lda, ldb, ldc); break;
      case 3: hipLaunchKernelGGL((gemm_f32<3>), g, dim3(256), 0, stream, A, B, bias, C, M, K, N, lda, ldb, ldc); break;
    }
  };

  // CSR build
  hipLaunchKernelGGL(fill_i32, dim3((NN + 255) / 256), dim3(256), 0, stream, DEG, 0, NN);
  hipLaunchKernelGGL(count_deg, dim3((ETOT + 255) / 256), dim3(256), 0, stream, ei, DEG);
  hipLaunchKernelGGL(scan_deg, dim3(1), dim3(1024), 0, stream, DEG, ROWPTR);
  hipLaunchKernelGGL(copy_i32, dim3((NN + 255) / 256), dim3(256), 0, stream, ROWPTR, CURSOR, NN);
  hipLaunchKernelGGL(fill_csr, dim3((ETOT + 255) / 256), dim3(256), 0, stream, ei, CURSOR, CSR);

  // weight transposes + x conversion
  auto launch_tw = [&](const float* W, unsigned short* WT, int K, int N, int Kp) {
    dim3 g((N + 31) / 32, (Kp + 31) / 32);
    hipLaunchKernelGGL(transpose_w, g, dim3(256), 0, stream, W, WT, K, N, Kp);
  };
  launch_tw(gW[0], WT1, 109, 768, 128);
  launch_tw(gW[1], WT2, 768, 1024, 768);
  launch_tw(gW[2], WT3, 1024, 1024, 1024);
  launch_tw(gW[3], WT4, 1024, 128, 1024);
  launch_tw(z1_W, WTZ, 19127, 1600, 19136);
  {
    size_t tot = (size_t)NN * 128;
    hipLaunchKernelGGL(conv_pad, dim3((unsigned)((tot + 255) / 256)), dim3(256), 0, stream,
                       x, XB, NN, 109, 128);
  }
  {
    size_t tot = (size_t)NB * 19136;
    hipLaunchKernelGGL(conv_pad, dim3((unsigned)((tot + 255) / 256)), dim3(256), 0, stream,
                       z, ZA, NB, 19127, 19136);
  }

  // GAT layers: XB (bf16) -> HLIN (bf16) -> aggregate -> XB
  const int Hs[4] = {8, 8, 8, 1};
  const int Cs[4] = {96, 128, 128, 128};
  const int Kp[4] = {128, 768, 1024, 1024};
  const unsigned short* WTs[4] = {WT1, WT2, WT3, WT4};
  for (int l = 0; l < 4; ++l) {
    int H = Hs[l], C = Cs[l], F = H * C;
    dim3 g(F / 128, NN / 128);
    hipLaunchKernelGGL((gemm_mfma<0, 1>), g, dim3(256), 0, stream,
                       XB, WTs[l], (const float*)nullptr, (void*)HLIN, F, Kp[l], Kp[l], Kp[l], F);
    int totNH = NN * H;
    hipLaunchKernelGGL(gat_scores_bf, dim3((totNH + 255) / 256), dim3(256), 0, stream,
                       HLIN, gas[l], gad[l], ALS, ALD, H, C, totNH);
    hipLaunchKernelGGL(fill_f32, dim3((totNH + 255) / 256), dim3(256), 0, stream, MBUF, -INFINITY, totNH);
    hipLaunchKernelGGL(fill_f32, dim3((totNH + 255) / 256), dim3(256), 0, stream, SB, 0.f, totNH);
    int totEH = ETOT * H;
    hipLaunchKernelGGL(edge_max, dim3((totEH + 255) / 256), dim3(256), 0, stream, ei, ALS, ALD, EB, MBUF, H, totEH);
    hipLaunchKernelGGL(edge_exp, dim3((totEH + 255) / 256), dim3(256), 0, stream, ei, EB, MBUF, SB, H, totEH);
    hipLaunchKernelGGL(gat_aggregate_bf, dim3(NN), dim3(256), 0, stream,
                       ROWPTR, CSR, ei, EB, SB, HLIN, gb[l], XB, H, C);
  }

  // global max pool (layer-4 output is in XB, [NN][128] bf16)
  hipLaunchKernelGGL(fill_f32, dim3((NB * 128 + 255) / 256), dim3(256), 0, stream, XG, -FLT_MAX, NB * 128);
  hipLaunchKernelGGL(pool_scatter_bf, dim3((NN * 128 + 255) / 256), dim3(256), 0, stream, XB, batch, XG, 128, NN * 128);

  // z1 via MFMA: ZMID[1024][1664(pad)] = relu(ZA @ WTZ^T + b)
  {
    dim3 g(1664 / 128, NB / 128);
    hipLaunchKernelGGL((gemm_mfma<1, 0>), g, dim3(256), 0, stream,
                       ZA, WTZ, z1_b, (void*)ZMID, 1600, 19136, 19136, 19136, 1664);
  }

  // small MLP chains (fp32)
  launch_gemm(1, XG, x5_W, x5_b, X5O, NB, 128, 64, 128, 64, 64);
  launch_gemm(1, X5O, x6_W, x6_b, CAT192 + 0, NB, 64, 64, 64, 64, 192);
  launch_gemm(1, w, w1_W, w1_b, WMID, NB, 750, 750, 750, 750, 750);
  launch_gemm(1, WMID, w2_W, w2_b, CAT192 + 64, NB, 750, 64, 750, 64, 192);
  launch_gemm(1, ZMID, z2_W, z2_b, CAT192 + 128, NB, 1600, 64, 1664, 64, 192);
  launch_gemm(1, v, v1_W, v1_b, VMID, NB, 1024, 256, 1024, 256, 256);
  launch_gemm(1, VMID, v2_W, v2_b, CAT128 + 64, NB, 256, 64, 256, 64, 128);
  launch_gemm(0, CAT192, agg_W, agg_b, CAT128 + 0, NB, 192, 64, 192, 64, 128);
  launch_gemm(3, CAT128, col_W, col_b, DRUG, NB, 128, 64, 128, 64, 64);
  launch_gemm(1, side, s1_W, s1_b, SEMID, NSIDE, 1050, 64, 1050, 64, 64);
  launch_gemm(2, SEMID, s2_W, s2_b, SE, NSIDE, 64, 64, 64, 64, 64);

  // normalize + similarity
  float* outp = (float*)d_out;
  float* DN = outp + (size_t)NB * NSIDE;
  float* SN = DN + (size_t)NB * 64;
  hipLaunchKernelGGL(rownorm, dim3(NB), dim3(64), 0, stream, DRUG, DN);
  hipLaunchKernelGGL(rownorm, dim3(NSIDE), dim3(64), 0, stream, SE, SN);
  hipLaunchKernelGGL(freq_k, dim3((NSIDE + 15) / 16, (NB + 15) / 16), dim3(256), 0, stream,
                     DN, SN, outp, NB, NSIDE);
}

// Round 3
// 2167.111 us; speedup vs baseline: 3.9339x; 1.1826x over previous
//
#include <hip/hip_runtime.h>
#include <math.h>
#include <float.h>

#define E0 131072
#define NN 32768
#define NB 1024
#define NSIDE 994
#define ETOT (E0 + NN)

typedef short bf16x8 __attribute__((ext_vector_type(8)));
typedef unsigned short ushort8 __attribute__((ext_vector_type(8)));
typedef float f32x4 __attribute__((ext_vector_type(4)));

__device__ inline float b2f(unsigned short u) { return __uint_as_float(((unsigned)u) << 16); }
__device__ inline unsigned short f2b(float f) {
  unsigned u = __float_as_uint(f);
  return (unsigned short)((u + 0x7fffu + ((u >> 16) & 1u)) >> 16);
}

__device__ inline void gload_lds16(const void* g, void* l) {
  __builtin_amdgcn_global_load_lds(
      (const __attribute__((address_space(1))) unsigned int*)g,
      (__attribute__((address_space(3))) unsigned int*)l, 16, 0, 0);
}

__device__ inline void atomicMaxF(float* addr, float val) {
  if (val >= 0.f) atomicMax((int*)addr, __float_as_int(val));
  else atomicMin((unsigned int*)addr, __float_as_uint(val));
}

__global__ void fill_f32(float* p, float v, int n) {
  int i = blockIdx.x * blockDim.x + threadIdx.x;
  if (i < n) p[i] = v;
}
__global__ void fill_i32(int* p, int v, int n) {
  int i = blockIdx.x * blockDim.x + threadIdx.x;
  if (i < n) p[i] = v;
}
__global__ void copy_i32(const int* s, int* d, int n) {
  int i = blockIdx.x * blockDim.x + threadIdx.x;
  if (i < n) d[i] = s[i];
}

// ---------------- fp32 -> bf16 conversion with column padding ----------------
__global__ void conv_pad(const float* __restrict__ in, unsigned short* __restrict__ out,
                         int rows, int C, int Cp) {
  size_t idx = (size_t)blockIdx.x * blockDim.x + threadIdx.x;
  size_t tot = (size_t)rows * Cp;
  if (idx >= tot) return;
  int r = (int)(idx / Cp), c = (int)(idx % Cp);
  out[idx] = (c < C) ? f2b(in[(size_t)r * C + c]) : (unsigned short)0;
}

// W [K][N] f32  ->  WT [N][Kp] bf16 (zero-pad k in [K,Kp))
__global__ __launch_bounds__(256) void transpose_w(const float* __restrict__ W,
                                                   unsigned short* __restrict__ WT,
                                                   int K, int N, int Kp) {
  __shared__ float t[32][33];
  int k0 = blockIdx.y * 32, n0 = blockIdx.x * 32;
  int tx = threadIdx.x & 31, ty = threadIdx.x >> 5;  // ty 0..7
  for (int r = ty; r < 32; r += 8) {
    int k = k0 + r, n = n0 + tx;
    t[r][tx] = (k < K && n < N) ? W[(size_t)k * N + n] : 0.f;
  }
  __syncthreads();
  for (int r = ty; r < 32; r += 8) {
    int n = n0 + r, k = k0 + tx;
    if (n < N && k < Kp) WT[(size_t)n * Kp + k] = f2b(t[tx][r]);
  }
}

// ---------------- CSR build over dst ----------------
__global__ void count_deg(const int* __restrict__ ei, int* deg) {
  int e = blockIdx.x * blockDim.x + threadIdx.x;
  if (e >= ETOT) return;
  int dst = (e < E0) ? ei[E0 + e] : (e - E0);
  atomicAdd(&deg[dst], 1);
}

__global__ void scan_deg(const int* __restrict__ deg, int* rowptr) {
  __shared__ int part[1024];
  int tid = threadIdx.x;
  const int chunk = NN / 1024;  // 32
  int base = tid * chunk;
  int local[chunk];
  int sum = 0;
#pragma unroll
  for (int i = 0; i < chunk; ++i) { local[i] = sum; sum += deg[base + i]; }
  part[tid] = sum;
  __syncthreads();
  for (int off = 1; off < 1024; off <<= 1) {
    int t = (tid >= off) ? part[tid - off] : 0;
    __syncthreads();
    part[tid] += t;
    __syncthreads();
  }
  int offset = part[tid] - sum;
#pragma unroll
  for (int i = 0; i < chunk; ++i) rowptr[base + i] = offset + local[i];
  if (tid == 1023) rowptr[NN] = offset + sum;
}

__global__ void fill_csr(const int* __restrict__ ei, int* cursor, int* csr) {
  int e = blockIdx.x * blockDim.x + threadIdx.x;
  if (e >= ETOT) return;
  int dst = (e < E0) ? ei[E0 + e] : (e - E0);
  int pos = atomicAdd(&cursor[dst], 1);
  csr[pos] = e;
}

// ---------------- bf16 MFMA GEMM: C = act(A[M,K] @ BT[N,K]^T + bias) ----------------
// 128x128 tile, BK=32, 4 waves (2x2), per-wave 64x64 via 4x4 of 16x16x32 MFMA.
// 1D grid (nwg % 8 == 0), gx = Npad/128; bijective XCD-chunked swizzle for L2 reuse.
// ACT: 0 none, 1 relu.  OBF: 1 -> bf16 out, 0 -> f32 out.
template <int ACT, int OBF>
__global__ __launch_bounds__(256) void gemm_mfma(
    const unsigned short* __restrict__ A, const unsigned short* __restrict__ BT,
    const float* __restrict__ bias, void* __restrict__ Cp,
    int Nreal, int K, int lda, int ldb, int ldc, int gx) {
  __shared__ unsigned short As[128 * 32];
  __shared__ unsigned short Bs[128 * 32];
  const int nwg = gridDim.x;
  const int chunk = nwg >> 3;
  const int bid = blockIdx.x;
  const int swz = (bid & 7) * chunk + (bid >> 3);
  const int bm = (swz / gx) * 128, bn = (swz % gx) * 128;
  const int tid = threadIdx.x;
  const int wv = tid >> 6, lane = tid & 63;
  const int sr = lane >> 2, sk = (lane & 3) * 8;
  const int r16 = lane & 15, kq = lane >> 4;
  const int wr = wv >> 1, wc = wv & 1;
  f32x4 acc[4][4];
#pragma unroll
  for (int i = 0; i < 4; ++i)
#pragma unroll
    for (int j = 0; j < 4; ++j) acc[i][j] = (f32x4){0.f, 0.f, 0.f, 0.f};

  const unsigned short* Abase = A + (size_t)bm * lda;
  const unsigned short* Bbase = BT + (size_t)bn * ldb;
  for (int k0 = 0; k0 < K; k0 += 32) {
    gload_lds16(Abase + (size_t)(wv * 16 + sr) * lda + k0 + sk, &As[wv * 512]);
    gload_lds16(Abase + (size_t)(64 + wv * 16 + sr) * lda + k0 + sk, &As[2048 + wv * 512]);
    gload_lds16(Bbase + (size_t)(wv * 16 + sr) * ldb + k0 + sk, &Bs[wv * 512]);
    gload_lds16(Bbase + (size_t)(64 + wv * 16 + sr) * ldb + k0 + sk, &Bs[2048 + wv * 512]);
    __syncthreads();
    bf16x8 af[4], bfr[4];
#pragma unroll
    for (int i = 0; i < 4; ++i)
      af[i] = *(const bf16x8*)&As[(wr * 64 + i * 16 + r16) * 32 + kq * 8];
#pragma unroll
    for (int j = 0; j < 4; ++j)
      bfr[j] = *(const bf16x8*)&Bs[(wc * 64 + j * 16 + r16) * 32 + kq * 8];
#pragma unroll
    for (int i = 0; i < 4; ++i)
#pragma unroll
      for (int j = 0; j < 4; ++j)
        acc[i][j] = __builtin_amdgcn_mfma_f32_16x16x32_bf16(af[i], bfr[j], acc[i][j], 0, 0, 0);
    __syncthreads();
  }
#pragma unroll
  for (int i = 0; i < 4; ++i) {
    int row = bm + wr * 64 + i * 16 + kq * 4;
#pragma unroll
    for (int j = 0; j < 4; ++j) {
      int col = bn + wc * 64 + j * 16 + r16;
      if (col >= Nreal) continue;
      float bv = bias ? bias[col] : 0.f;
#pragma unroll
      for (int r = 0; r < 4; ++r) {
        float v = acc[i][j][r] + bv;
        if (ACT == 1) v = v > 0.f ? v : 0.f;
        if (OBF) ((unsigned short*)Cp)[(size_t)(row + r) * ldc + col] = f2b(v);
        else ((float*)Cp)[(size_t)(row + r) * ldc + col] = v;
      }
    }
  }
}

// ---------------- split-K MFMA GEMM for z1 ----------------
// M=1024, Npad=1664 (Nreal 1600), K=19136 (598 k-steps). 8 K-slices, uneven 75/74.
// grid = 832 1D; s = bid&7 so (assumed) XCD round-robin puts one K-slice per XCD.
// Writes f32 partials (no bias/act) to PART[s][1024][1664].
__global__ __launch_bounds__(256) void gemm_mfma_sk(
    const unsigned short* __restrict__ A, const unsigned short* __restrict__ BT,
    float* __restrict__ PART, int lda, int ldb, int ldc) {
  __shared__ unsigned short As[128 * 32];
  __shared__ unsigned short Bs[128 * 32];
  const int bid = blockIdx.x;
  const int s = bid & 7;
  const int pos = bid >> 3;            // 0..103
  const int bm = (pos / 13) * 128, bn = (pos % 13) * 128;
  const int base = s * 74 + (s < 6 ? s : 6);
  const int nsteps = 74 + (s < 6 ? 1 : 0);
  const int tid = threadIdx.x;
  const int wv = tid >> 6, lane = tid & 63;
  const int sr = lane >> 2, sk = (lane & 3) * 8;
  const int r16 = lane & 15, kq = lane >> 4;
  const int wr = wv >> 1, wc = wv & 1;
  f32x4 acc[4][4];
#pragma unroll
  for (int i = 0; i < 4; ++i)
#pragma unroll
    for (int j = 0; j < 4; ++j) acc[i][j] = (f32x4){0.f, 0.f, 0.f, 0.f};

  const unsigned short* Abase = A + (size_t)bm * lda;
  const unsigned short* Bbase = BT + (size_t)bn * ldb;
  for (int ks = 0; ks < nsteps; ++ks) {
    int k0 = (base + ks) * 32;
    gload_lds16(Abase + (size_t)(wv * 16 + sr) * lda + k0 + sk, &As[wv * 512]);
    gload_lds16(Abase + (size_t)(64 + wv * 16 + sr) * lda + k0 + sk, &As[2048 + wv * 512]);
    gload_lds16(Bbase + (size_t)(wv * 16 + sr) * ldb + k0 + sk, &Bs[wv * 512]);
    gload_lds16(Bbase + (size_t)(64 + wv * 16 + sr) * ldb + k0 + sk, &Bs[2048 + wv * 512]);
    __syncthreads();
    bf16x8 af[4], bfr[4];
#pragma unroll
    for (int i = 0; i < 4; ++i)
      af[i] = *(const bf16x8*)&As[(wr * 64 + i * 16 + r16) * 32 + kq * 8];
#pragma unroll
    for (int j = 0; j < 4; ++j)
      bfr[j] = *(const bf16x8*)&Bs[(wc * 64 + j * 16 + r16) * 32 + kq * 8];
#pragma unroll
    for (int i = 0; i < 4; ++i)
#pragma unroll
      for (int j = 0; j < 4; ++j)
        acc[i][j] = __builtin_amdgcn_mfma_f32_16x16x32_bf16(af[i], bfr[j], acc[i][j], 0, 0, 0);
    __syncthreads();
  }
  float* out = PART + (size_t)s * 1024 * ldc;
#pragma unroll
  for (int i = 0; i < 4; ++i) {
    int row = bm + wr * 64 + i * 16 + kq * 4;
#pragma unroll
    for (int j = 0; j < 4; ++j) {
      int col = bn + wc * 64 + j * 16 + r16;
      if (col >= 1600) continue;
#pragma unroll
      for (int r = 0; r < 4; ++r)
        out[(size_t)(row + r) * ldc + col] = acc[i][j][r];
    }
  }
}

// reduce 8 K-slice partials + bias + relu -> ZMID f32 [1024][1664] (cols <1600)
__global__ void zred(const float* __restrict__ PART, const float* __restrict__ bias,
                     float* __restrict__ ZMID) {
  int idx = blockIdx.x * blockDim.x + threadIdx.x;
  if (idx >= 1024 * 1600) return;
  int r = idx / 1600, c = idx - r * 1600;
  size_t o = (size_t)r * 1664 + c;
  float s = 0.f;
#pragma unroll
  for (int k = 0; k < 8; ++k) s += PART[(size_t)k * 1024 * 1664 + o];
  s += bias[c];
  ZMID[o] = s > 0.f ? s : 0.f;
}

// ---------------- fp32 GEMM for small layers ----------------
template <int ACT>
__global__ __launch_bounds__(256) void gemm_f32(
    const float* __restrict__ A, const float* __restrict__ B,
    const float* __restrict__ bias, float* __restrict__ C,
    int M, int K, int N, int lda, int ldb, int ldc) {
  __shared__ float As[16][64];
  __shared__ float Bs[16][64];
  const int tid = threadIdx.x;
  const int tx = tid & 15, ty = tid >> 4;
  const int bm = blockIdx.y * 64, bn = blockIdx.x * 64;
  float acc[4][4] = {{0.f}};
  for (int k0 = 0; k0 < K; k0 += 16) {
#pragma unroll
    for (int t = 0; t < 4; ++t) {
      int idx = tid * 4 + t;
      int r = idx >> 4, c = idx & 15;
      float va = 0.f;
      if (bm + r < M && k0 + c < K) va = A[(size_t)(bm + r) * lda + (k0 + c)];
      As[c][r] = va;
      int rb = idx >> 6, cb = idx & 63;
      float vb = 0.f;
      if (k0 + rb < K && bn + cb < N) vb = B[(size_t)(k0 + rb) * ldb + (bn + cb)];
      Bs[rb][cb] = vb;
    }
    __syncthreads();
#pragma unroll
    for (int kk = 0; kk < 16; ++kk) {
      float4 a4 = *reinterpret_cast<const float4*>(&As[kk][ty * 4]);
      float4 b4 = *reinterpret_cast<const float4*>(&Bs[kk][tx * 4]);
      float a[4] = {a4.x, a4.y, a4.z, a4.w};
      float b[4] = {b4.x, b4.y, b4.z, b4.w};
#pragma unroll
      for (int i = 0; i < 4; ++i)
#pragma unroll
        for (int j = 0; j < 4; ++j) acc[i][j] = fmaf(a[i], b[j], acc[i][j]);
    }
    __syncthreads();
  }
#pragma unroll
  for (int i = 0; i < 4; ++i) {
    int r = bm + ty * 4 + i;
    if (r >= M) continue;
#pragma unroll
    for (int j = 0; j < 4; ++j) {
      int cc = bn + tx * 4 + j;
      if (cc >= N) continue;
      float v = acc[i][j];
      if (bias) v += bias[cc];
      if (ACT == 1) v = v > 0.f ? v : 0.f;
      else if (ACT == 2) v = tanhf(v);
      else if (ACT == 3) v = fabsf(tanhf(v));
      C[(size_t)r * ldc + cc] = v;
    }
  }
}

// ---------------- GAT pieces (bf16 features) ----------------
__global__ void gat_scores_bf(const unsigned short* __restrict__ hlin,
                              const float* __restrict__ a_s, const float* __restrict__ a_d,
                              float* __restrict__ als, float* __restrict__ ald,
                              int H, int C, int tot) {
  int idx = blockIdx.x * blockDim.x + threadIdx.x;
  if (idx >= tot) return;
  int n = idx / H, h = idx - n * H;
  const unsigned short* base = hlin + (size_t)n * H * C + (size_t)h * C;
  const float* as = a_s + h * C;
  const float* ad = a_d + h * C;
  float ss = 0.f, sd = 0.f;
  for (int c = 0; c < C; c += 8) {
    ushort8 v = *(const ushort8*)(base + c);
#pragma unroll
    for (int t = 0; t < 8; ++t) {
      float f = b2f(v[t]);
      ss = fmaf(f, as[c + t], ss);
      sd = fmaf(f, ad[c + t], sd);
    }
  }
  als[idx] = ss;
  ald[idx] = sd;
}

__global__ void edge_max(const int* __restrict__ ei, const float* __restrict__ als,
                         const float* __restrict__ ald, float* __restrict__ eb,
                         float* mb, int H, int tot) {
  int idx = blockIdx.x * blockDim.x + threadIdx.x;
  if (idx >= tot) return;
  int e = idx / H, h = idx - e * H;
  int src, dst;
  if (e < E0) { src = ei[e]; dst = ei[E0 + e]; } else { src = dst = e - E0; }
  float v = als[src * H + h] + ald[dst * H + h];
  v = (v >= 0.f) ? v : 0.2f * v;  // leaky_relu 0.2
  eb[idx] = v;
  atomicMaxF(&mb[dst * H + h], v);
}

__global__ void edge_exp(const int* __restrict__ ei, float* __restrict__ eb,
                         const float* __restrict__ mb, float* sb, int H, int tot) {
  int idx = blockIdx.x * blockDim.x + threadIdx.x;
  if (idx >= tot) return;
  int e = idx / H, h = idx - e * H;
  int dst = (e < E0) ? ei[E0 + e] : (e - E0);
  float p = expf(eb[idx] - mb[dst * H + h]);
  eb[idx] = p;
  atomicAdd(&sb[dst * H + h], p);
}

__global__ __launch_bounds__(256) void gat_aggregate_bf(
    const int* __restrict__ rowptr, const int* __restrict__ csr,
    const int* __restrict__ ei, const float* __restrict__ eb,
    const float* __restrict__ sb, const unsigned short* __restrict__ hlin,
    const float* __restrict__ bias, unsigned short* __restrict__ out, int H, int C) {
  int n = blockIdx.x;
  int F = H * C;
  int start = rowptr[n], end = rowptr[n + 1];
  for (int c = threadIdx.x; c < F; c += blockDim.x) {
    int h = c / C;
    float inv_s = 1.f / sb[n * H + h];
    float acc = 0.f;
    for (int k = start; k < end; ++k) {
      int eid = csr[k];
      int src = (eid < E0) ? ei[eid] : (eid - E0);
      float p = eb[(size_t)eid * H + h];
      acc = fmaf(p, b2f(hlin[(size_t)src * F + c]), acc);
    }
    float val = acc * inv_s + bias[c];
    out[(size_t)n * F + c] = f2b(val > 0.f ? val : 0.f);  // relu
  }
}

__global__ void pool_scatter_bf(const unsigned short* __restrict__ h,
                                const int* __restrict__ batch, float* xg, int F, int tot) {
  int idx = blockIdx.x * blockDim.x + threadIdx.x;
  if (idx >= tot) return;
  int n = idx / F, f = idx - n * F;
  atomicMaxF(&xg[batch[n] * F + f], b2f(h[idx]));
}

// rows of 64, one wave per row
__global__ void rownorm(const float* __restrict__ in, float* __restrict__ outp) {
  int r = blockIdx.x, lane = threadIdx.x;
  float v = in[r * 64 + lane];
  float ss = v * v;
#pragma unroll
  for (int off = 1; off < 64; off <<= 1) ss += __shfl_xor(ss, off);
  float nrm = fmaxf(sqrtf(ss), 1e-12f);
  outp[r * 64 + lane] = v / nrm;
}

// C[M,N] = 5 * A[M,64] @ B[N,64]^T
__global__ __launch_bounds__(256) void freq_k(const float* __restrict__ dn,
                                              const float* __restrict__ sn,
                                              float* __restrict__ C, int M, int N) {
  __shared__ float As[16][64];
  __shared__ float Bs[16][65];
  int tid = threadIdx.x;
  int tx = tid & 15, ty = tid >> 4;
  int bi = blockIdx.y * 16, bj = blockIdx.x * 16;
#pragma unroll
  for (int t = 0; t < 4; ++t) {
    int idx = tid * 4 + t;
    int r = idx >> 6, c = idx & 63;
    As[r][c] = (bi + r < M) ? dn[(bi + r) * 64 + c] : 0.f;
    Bs[r][c] = (bj + r < N) ? sn[(bj + r) * 64 + c] : 0.f;
  }
  __syncthreads();
  float acc = 0.f;
#pragma unroll
  for (int k = 0; k < 64; ++k) acc = fmaf(As[ty][k], Bs[tx][k], acc);
  if (bi + ty < M && bj + tx < N) C[(size_t)(bi + ty) * N + (bj + tx)] = 5.f * acc;
}

// ---------------- launch ----------------
extern "C" void kernel_launch(void* const* d_in, const int* in_sizes, int n_in,
                              void* d_out, int out_size, void* d_ws, size_t ws_size,
                              hipStream_t stream) {
  const float* x = (const float*)d_in[0];
  const int* ei = (const int*)d_in[1];
  const int* batch = (const int*)d_in[2];
  const float* w = (const float*)d_in[3];
  const float* z = (const float*)d_in[4];
  const float* v = (const float*)d_in[5];
  const float* side = (const float*)d_in[6];
  const float* gW[4] = {(const float*)d_in[7], (const float*)d_in[11],
                        (const float*)d_in[15], (const float*)d_in[19]};
  const float* gas[4] = {(const float*)d_in[8], (const float*)d_in[12],
                         (const float*)d_in[16], (const float*)d_in[20]};
  const float* gad[4] = {(const float*)d_in[9], (const float*)d_in[13],
                         (const float*)d_in[17], (const float*)d_in[21]};
  const float* gb[4] = {(const float*)d_in[10], (const float*)d_in[14],
                        (const float*)d_in[18], (const float*)d_in[22]};
  const float* x5_W = (const float*)d_in[23]; const float* x5_b = (const float*)d_in[24];
  const float* x6_W = (const float*)d_in[25]; const float* x6_b = (const float*)d_in[26];
  const float* w1_W = (const float*)d_in[27]; const float* w1_b = (const float*)d_in[28];
  const float* w2_W = (const float*)d_in[29]; const float* w2_b = (const float*)d_in[30];
  const float* z1_W = (const float*)d_in[31]; const float* z1_b = (const float*)d_in[32];
  const float* z2_W = (const float*)d_in[33]; const float* z2_b = (const float*)d_in[34];
  const float* v1_W = (const float*)d_in[35]; const float* v1_b = (const float*)d_in[36];
  const float* v2_W = (const float*)d_in[37]; const float* v2_b = (const float*)d_in[38];
  const float* agg_W = (const float*)d_in[39]; const float* agg_b = (const float*)d_in[40];
  const float* col_W = (const float*)d_in[41]; const float* col_b = (const float*)d_in[42];
  const float* s1_W = (const float*)d_in[43]; const float* s1_b = (const float*)d_in[44];
  const float* s2_W = (const float*)d_in[45]; const float* s2_b = (const float*)d_in[46];

  char* wsb = (char*)d_ws;
  size_t off = 0;
  auto alloc = [&](size_t bytes) {
    void* p = wsb + off;
    off = (off + bytes + 255) & ~(size_t)255;
    return p;
  };
  unsigned short* HLIN = (unsigned short*)alloc((size_t)NN * 1024 * 2);  // also aliased as PART after GAT
  unsigned short* XB = (unsigned short*)alloc((size_t)NN * 1024 * 2);
  unsigned short* WT1 = (unsigned short*)alloc((size_t)768 * 128 * 2);
  unsigned short* WT2 = (unsigned short*)alloc((size_t)1024 * 768 * 2);
  unsigned short* WT3 = (unsigned short*)alloc((size_t)1024 * 1024 * 2);
  unsigned short* WT4 = (unsigned short*)alloc((size_t)128 * 1024 * 2);
  unsigned short* WTZ = (unsigned short*)alloc((size_t)1664 * 19136 * 2);
  unsigned short* ZA = (unsigned short*)alloc((size_t)1024 * 19136 * 2);
  float* ZMID = (float*)alloc((size_t)NB * 1664 * 4);
  float* EB = (float*)alloc((size_t)ETOT * 8 * 4);
  float* ALS = (float*)alloc((size_t)NN * 8 * 4);
  float* ALD = (float*)alloc((size_t)NN * 8 * 4);
  float* MBUF = (float*)alloc((size_t)NN * 8 * 4);
  float* SB = (float*)alloc((size_t)NN * 8 * 4);
  float* WMID = (float*)alloc((size_t)NB * 750 * 4);
  float* VMID = (float*)alloc((size_t)NB * 256 * 4);
  float* XG = (float*)alloc((size_t)NB * 128 * 4);
  float* X5O = (float*)alloc((size_t)NB * 64 * 4);
  float* CAT192 = (float*)alloc((size_t)NB * 192 * 4);
  float* CAT128 = (float*)alloc((size_t)NB * 128 * 4);
  float* DRUG = (float*)alloc((size_t)NB * 64 * 4);
  float* SEMID = (float*)alloc((size_t)NSIDE * 64 * 4);
  float* SE = (float*)alloc((size_t)NSIDE * 64 * 4);
  int* DEG = (int*)alloc((size_t)NN * 4);
  int* ROWPTR = (int*)alloc((size_t)(NN + 1) * 4);
  int* CURSOR = (int*)alloc((size_t)NN * 4);
  int* CSR = (int*)alloc((size_t)ETOT * 4);
  // PART aliases HLIN (dead after GAT layer 4): 8*1024*1664*4 = 54.5MB <= 67MB
  float* PART = (float*)HLIN;

  auto launch_gemm = [&](int act, const float* A, const float* B, const float* bias,
                         float* C, int M, int K, int N, int lda, int ldb, int ldc) {
    dim3 g((N + 63) / 64, (M + 63) / 64);
    switch (act) {
      case 0: hipLaunchKernelGGL((gemm_f32<0>), g, dim3(256), 0, stream, A, B, bias, C, M, K, N, lda, ldb, ldc); break;
      case 1: hipLaunchKernelGGL((gemm_f32<1>), g, dim3(256), 0, stream, A, B, bias, C, M, K, N, lda, ldb, ldc); break;
      case 2: hipLaunchKernelGGL((gemm_f32<2>), g, dim3(256), 0, stream, A, B, bias, C, M, K, N, lda, ldb, ldc); break;
      case 3: hipLaunchKernelGGL((gemm_f32<3>), g, dim3(256), 0, stream, A, B, bias, C, M, K, N, lda, ldb, ldc); break;
    }
  };

  // CSR build
  hipLaunchKernelGGL(fill_i32, dim3((NN + 255) / 256), dim3(256), 0, stream, DEG, 0, NN);
  hipLaunchKernelGGL(count_deg, dim3((ETOT + 255) / 256), dim3(256), 0, stream, ei, DEG);
  hipLaunchKernelGGL(scan_deg, dim3(1), dim3(1024), 0, stream, DEG, ROWPTR);
  hipLaunchKernelGGL(copy_i32, dim3((NN + 255) / 256), dim3(256), 0, stream, ROWPTR, CURSOR, NN);
  hipLaunchKernelGGL(fill_csr, dim3((ETOT + 255) / 256), dim3(256), 0, stream, ei, CURSOR, CSR);

  // weight transposes + conversions
  auto launch_tw = [&](const float* W, unsigned short* WT, int K, int N, int Kp) {
    dim3 g((N + 31) / 32, (Kp + 31) / 32);
    hipLaunchKernelGGL(transpose_w, g, dim3(256), 0, stream, W, WT, K, N, Kp);
  };
  launch_tw(gW[0], WT1, 109, 768, 128);
  launch_tw(gW[1], WT2, 768, 1024, 768);
  launch_tw(gW[2], WT3, 1024, 1024, 1024);
  launch_tw(gW[3], WT4, 1024, 128, 1024);
  launch_tw(z1_W, WTZ, 19127, 1600, 19136);
  {
    size_t tot = (size_t)NN * 128;
    hipLaunchKernelGGL(conv_pad, dim3((unsigned)((tot + 255) / 256)), dim3(256), 0, stream,
                       x, XB, NN, 109, 128);
  }
  {
    size_t tot = (size_t)NB * 19136;
    hipLaunchKernelGGL(conv_pad, dim3((unsigned)((tot + 255) / 256)), dim3(256), 0, stream,
                       z, ZA, NB, 19127, 19136);
  }

  // GAT layers: XB (bf16) -> HLIN (bf16) -> aggregate -> XB
  const int Hs[4] = {8, 8, 8, 1};
  const int Cs[4] = {96, 128, 128, 128};
  const int Kp[4] = {128, 768, 1024, 1024};
  const unsigned short* WTs[4] = {WT1, WT2, WT3, WT4};
  for (int l = 0; l < 4; ++l) {
    int H = Hs[l], C = Cs[l], F = H * C;
    int gx = F / 128;
    int nwg = gx * (NN / 128);
    hipLaunchKernelGGL((gemm_mfma<0, 1>), dim3(nwg), dim3(256), 0, stream,
                       XB, WTs[l], (const float*)nullptr, (void*)HLIN, F, Kp[l], Kp[l], Kp[l], F, gx);
    int totNH = NN * H;
    hipLaunchKernelGGL(gat_scores_bf, dim3((totNH + 255) / 256), dim3(256), 0, stream,
                       HLIN, gas[l], gad[l], ALS, ALD, H, C, totNH);
    hipLaunchKernelGGL(fill_f32, dim3((totNH + 255) / 256), dim3(256), 0, stream, MBUF, -INFINITY, totNH);
    hipLaunchKernelGGL(fill_f32, dim3((totNH + 255) / 256), dim3(256), 0, stream, SB, 0.f, totNH);
    int totEH = ETOT * H;
    hipLaunchKernelGGL(edge_max, dim3((totEH + 255) / 256), dim3(256), 0, stream, ei, ALS, ALD, EB, MBUF, H, totEH);
    hipLaunchKernelGGL(edge_exp, dim3((totEH + 255) / 256), dim3(256), 0, stream, ei, EB, MBUF, SB, H, totEH);
    hipLaunchKernelGGL(gat_aggregate_bf, dim3(NN), dim3(256), 0, stream,
                       ROWPTR, CSR, ei, EB, SB, HLIN, gb[l], XB, H, C);
  }

  // global max pool (layer-4 output in XB, [NN][128] bf16)
  hipLaunchKernelGGL(fill_f32, dim3((NB * 128 + 255) / 256), dim3(256), 0, stream, XG, -FLT_MAX, NB * 128);
  hipLaunchKernelGGL(pool_scatter_bf, dim3((NN * 128 + 255) / 256), dim3(256), 0, stream, XB, batch, XG, 128, NN * 128);

  // z1 via split-K MFMA (HLIN dead -> PART): 832 WGs, 8 K-slices
  hipLaunchKernelGGL(gemm_mfma_sk, dim3(832), dim3(256), 0, stream,
                     ZA, WTZ, PART, 19136, 19136, 1664);
  hipLaunchKernelGGL(zred, dim3((1024 * 1600 + 255) / 256), dim3(256), 0, stream,
                     PART, z1_b, ZMID);

  // small MLP chains (fp32)
  launch_gemm(1, XG, x5_W, x5_b, X5O, NB, 128, 64, 128, 64, 64);
  launch_gemm(1, X5O, x6_W, x6_b, CAT192 + 0, NB, 64, 64, 64, 64, 192);
  launch_gemm(1, w, w1_W, w1_b, WMID, NB, 750, 750, 750, 750, 750);
  launch_gemm(1, WMID, w2_W, w2_b, CAT192 + 64, NB, 750, 64, 750, 64, 192);
  launch_gemm(1, ZMID, z2_W, z2_b, CAT192 + 128, NB, 1600, 64, 1664, 64, 192);
  launch_gemm(1, v, v1_W, v1_b, VMID, NB, 1024, 256, 1024, 256, 256);
  launch_gemm(1, VMID, v2_W, v2_b, CAT128 + 64, NB, 256, 64, 256, 64, 128);
  launch_gemm(0, CAT192, agg_W, agg_b, CAT128 + 0, NB, 192, 64, 192, 64, 128);
  launch_gemm(3, CAT128, col_W, col_b, DRUG, NB, 128, 64, 128, 64, 64);
  launch_gemm(1, side, s1_W, s1_b, SEMID, NSIDE, 1050, 64, 1050, 64, 64);
  launch_gemm(2, SEMID, s2_W, s2_b, SE, NSIDE, 64, 64, 64, 64, 64);

  // normalize + similarity
  float* outp = (float*)d_out;
  float* DN = outp + (size_t)NB * NSIDE;
  float* SN = DN + (size_t)NB * 64;
  hipLaunchKernelGGL(rownorm, dim3(NB), dim3(64), 0, stream, DRUG, DN);
  hipLaunchKernelGGL(rownorm, dim3(NSIDE), dim3(64), 0, stream, SE, SN);
  hipLaunchKernelGGL(freq_k, dim3((NSIDE + 15) / 16, (NB + 15) / 16), dim3(256), 0, stream,
                     DN, SN, outp, NB, NSIDE);
}

// Round 4
// 1405.139 us; speedup vs baseline: 6.0672x; 1.5423x over previous
//
#include <hip/hip_runtime.h>
#include <math.h>
#include <float.h>

#define E0 131072
#define NN 32768
#define NB 1024
#define NSIDE 994
#define ETOT (E0 + NN)

typedef short bf16x8 __attribute__((ext_vector_type(8)));
typedef unsigned short ushort8 __attribute__((ext_vector_type(8)));
typedef float f32x4 __attribute__((ext_vector_type(4)));

__device__ inline float b2f(unsigned short u) { return __uint_as_float(((unsigned)u) << 16); }
__device__ inline unsigned short f2b(float f) {
  unsigned u = __float_as_uint(f);
  return (unsigned short)((u + 0x7fffu + ((u >> 16) & 1u)) >> 16);
}

__device__ inline void gload_lds16(const void* g, void* l) {
  __builtin_amdgcn_global_load_lds(
      (const __attribute__((address_space(1))) unsigned int*)g,
      (__attribute__((address_space(3))) unsigned int*)l, 16, 0, 0);
}

__device__ inline void atomicMaxF(float* addr, float val) {
  if (val >= 0.f) atomicMax((int*)addr, __float_as_int(val));
  else atomicMin((unsigned int*)addr, __float_as_uint(val));
}

__global__ void fill_f32(float* p, float v, int n) {
  int i = blockIdx.x * blockDim.x + threadIdx.x;
  if (i < n) p[i] = v;
}
__global__ void fill_i32(int* p, int v, int n) {
  int i = blockIdx.x * blockDim.x + threadIdx.x;
  if (i < n) p[i] = v;
}
__global__ void copy_i32(const int* s, int* d, int n) {
  int i = blockIdx.x * blockDim.x + threadIdx.x;
  if (i < n) d[i] = s[i];
}

// fp32 [RrealxC] -> bf16 [rowsOut x Cp], zero pad rows >= Rreal and cols >= C
__global__ void conv_pad(const float* __restrict__ in, unsigned short* __restrict__ out,
                         int rowsOut, int Rreal, int C, int Cp) {
  size_t idx = (size_t)blockIdx.x * blockDim.x + threadIdx.x;
  size_t tot = (size_t)rowsOut * Cp;
  if (idx >= tot) return;
  int r = (int)(idx / Cp), c = (int)(idx % Cp);
  out[idx] = (r < Rreal && c < C) ? f2b(in[(size_t)r * C + c]) : (unsigned short)0;
}

// W [K][N] f32 -> WT [Npad][Kp] bf16; rows n in [N,Npad) and cols k in [K,Kp) zeroed
__global__ __launch_bounds__(256) void transpose_w(const float* __restrict__ W,
                                                   unsigned short* __restrict__ WT,
                                                   int K, int N, int Kp, int Npad) {
  __shared__ float t[32][33];
  int k0 = blockIdx.y * 32, n0 = blockIdx.x * 32;
  int tx = threadIdx.x & 31, ty = threadIdx.x >> 5;
  for (int r = ty; r < 32; r += 8) {
    int k = k0 + r, n = n0 + tx;
    t[r][tx] = (k < K && n < N) ? W[(size_t)k * N + n] : 0.f;
  }
  __syncthreads();
  for (int r = ty; r < 32; r += 8) {
    int n = n0 + r, k = k0 + tx;
    if (n < Npad && k < Kp) WT[(size_t)n * Kp + k] = (n < N) ? f2b(t[tx][r]) : (unsigned short)0;
  }
}

// ---------------- CSR build over dst ----------------
__global__ void count_deg(const int* __restrict__ ei, int* deg) {
  int e = blockIdx.x * blockDim.x + threadIdx.x;
  if (e >= ETOT) return;
  int dst = (e < E0) ? ei[E0 + e] : (e - E0);
  atomicAdd(&deg[dst], 1);
}

__global__ void scan_deg(const int* __restrict__ deg, int* rowptr) {
  __shared__ int part[1024];
  int tid = threadIdx.x;
  const int chunk = NN / 1024;  // 32
  int base = tid * chunk;
  int local[chunk];
  int sum = 0;
#pragma unroll
  for (int i = 0; i < chunk; ++i) { local[i] = sum; sum += deg[base + i]; }
  part[tid] = sum;
  __syncthreads();
  for (int off = 1; off < 1024; off <<= 1) {
    int t = (tid >= off) ? part[tid - off] : 0;
    __syncthreads();
    part[tid] += t;
    __syncthreads();
  }
  int offset = part[tid] - sum;
#pragma unroll
  for (int i = 0; i < chunk; ++i) rowptr[base + i] = offset + local[i];
  if (tid == 1023) rowptr[NN] = offset + sum;
}

__global__ void fill_csr(const int* __restrict__ ei, int* cursor, int* csr) {
  int e = blockIdx.x * blockDim.x + threadIdx.x;
  if (e >= ETOT) return;
  int dst = (e < E0) ? ei[E0 + e] : (e - E0);
  int pos = atomicAdd(&cursor[dst], 1);
  csr[pos] = e;
}

// ---------------- bf16 MFMA GEMM ----------------
// 128x128 tile, BK=32, 4 waves; 1D grid (nwg%8==0) with XCD-chunked swizzle.
// ACT: 0 none, 1 relu, 2 tanh, 3 abs(tanh). OBF: 1 bf16 out, 0 f32 out.
// zpad: for cols in [Nreal, Npad): 1 -> store zero, 0 -> skip store.
template <int ACT, int OBF>
__global__ __launch_bounds__(256) void gemm_mfma(
    const unsigned short* __restrict__ A, const unsigned short* __restrict__ BT,
    const float* __restrict__ bias, void* __restrict__ Cp,
    int Nreal, int K, int lda, int ldb, int ldc, int gx, int zpad) {
  __shared__ unsigned short As[128 * 32];
  __shared__ unsigned short Bs[128 * 32];
  const int nwg = gridDim.x;
  const int chunk = nwg >> 3;
  const int bid = blockIdx.x;
  const int swz = (bid & 7) * chunk + (bid >> 3);
  const int bm = (swz / gx) * 128, bn = (swz % gx) * 128;
  const int tid = threadIdx.x;
  const int wv = tid >> 6, lane = tid & 63;
  const int sr = lane >> 2, sk = (lane & 3) * 8;
  const int r16 = lane & 15, kq = lane >> 4;
  const int wr = wv >> 1, wc = wv & 1;
  f32x4 acc[4][4];
#pragma unroll
  for (int i = 0; i < 4; ++i)
#pragma unroll
    for (int j = 0; j < 4; ++j) acc[i][j] = (f32x4){0.f, 0.f, 0.f, 0.f};

  const unsigned short* Abase = A + (size_t)bm * lda;
  const unsigned short* Bbase = BT + (size_t)bn * ldb;
  for (int k0 = 0; k0 < K; k0 += 32) {
    gload_lds16(Abase + (size_t)(wv * 16 + sr) * lda + k0 + sk, &As[wv * 512]);
    gload_lds16(Abase + (size_t)(64 + wv * 16 + sr) * lda + k0 + sk, &As[2048 + wv * 512]);
    gload_lds16(Bbase + (size_t)(wv * 16 + sr) * ldb + k0 + sk, &Bs[wv * 512]);
    gload_lds16(Bbase + (size_t)(64 + wv * 16 + sr) * ldb + k0 + sk, &Bs[2048 + wv * 512]);
    __syncthreads();
    bf16x8 af[4], bfr[4];
#pragma unroll
    for (int i = 0; i < 4; ++i)
      af[i] = *(const bf16x8*)&As[(wr * 64 + i * 16 + r16) * 32 + kq * 8];
#pragma unroll
    for (int j = 0; j < 4; ++j)
      bfr[j] = *(const bf16x8*)&Bs[(wc * 64 + j * 16 + r16) * 32 + kq * 8];
#pragma unroll
    for (int i = 0; i < 4; ++i)
#pragma unroll
      for (int j = 0; j < 4; ++j)
        acc[i][j] = __builtin_amdgcn_mfma_f32_16x16x32_bf16(af[i], bfr[j], acc[i][j], 0, 0, 0);
    __syncthreads();
  }
#pragma unroll
  for (int i = 0; i < 4; ++i) {
    int row = bm + wr * 64 + i * 16 + kq * 4;
#pragma unroll
    for (int j = 0; j < 4; ++j) {
      int col = bn + wc * 64 + j * 16 + r16;
      bool real = col < Nreal;
      if (!real && !zpad) continue;
      float bv = (bias && real) ? bias[col] : 0.f;
#pragma unroll
      for (int r = 0; r < 4; ++r) {
        float v = acc[i][j][r] + bv;
        if (ACT == 1) v = v > 0.f ? v : 0.f;
        else if (ACT == 2) v = tanhf(v);
        else if (ACT == 3) v = fabsf(tanhf(v));
        if (!real) v = 0.f;
        if (OBF) ((unsigned short*)Cp)[(size_t)(row + r) * ldc + col] = f2b(v);
        else ((float*)Cp)[(size_t)(row + r) * ldc + col] = v;
      }
    }
  }
}

// ---------------- split-K MFMA GEMM for z1 ----------------
__global__ __launch_bounds__(256) void gemm_mfma_sk(
    const unsigned short* __restrict__ A, const unsigned short* __restrict__ BT,
    float* __restrict__ PART, int lda, int ldb, int ldc) {
  __shared__ unsigned short As[128 * 32];
  __shared__ unsigned short Bs[128 * 32];
  const int bid = blockIdx.x;
  const int s = bid & 7;
  const int pos = bid >> 3;
  const int bm = (pos / 13) * 128, bn = (pos % 13) * 128;
  const int base = s * 74 + (s < 6 ? s : 6);
  const int nsteps = 74 + (s < 6 ? 1 : 0);
  const int tid = threadIdx.x;
  const int wv = tid >> 6, lane = tid & 63;
  const int sr = lane >> 2, sk = (lane & 3) * 8;
  const int r16 = lane & 15, kq = lane >> 4;
  const int wr = wv >> 1, wc = wv & 1;
  f32x4 acc[4][4];
#pragma unroll
  for (int i = 0; i < 4; ++i)
#pragma unroll
    for (int j = 0; j < 4; ++j) acc[i][j] = (f32x4){0.f, 0.f, 0.f, 0.f};

  const unsigned short* Abase = A + (size_t)bm * lda;
  const unsigned short* Bbase = BT + (size_t)bn * ldb;
  for (int ks = 0; ks < nsteps; ++ks) {
    int k0 = (base + ks) * 32;
    gload_lds16(Abase + (size_t)(wv * 16 + sr) * lda + k0 + sk, &As[wv * 512]);
    gload_lds16(Abase + (size_t)(64 + wv * 16 + sr) * lda + k0 + sk, &As[2048 + wv * 512]);
    gload_lds16(Bbase + (size_t)(wv * 16 + sr) * ldb + k0 + sk, &Bs[wv * 512]);
    gload_lds16(Bbase + (size_t)(64 + wv * 16 + sr) * ldb + k0 + sk, &Bs[2048 + wv * 512]);
    __syncthreads();
    bf16x8 af[4], bfr[4];
#pragma unroll
    for (int i = 0; i < 4; ++i)
      af[i] = *(const bf16x8*)&As[(wr * 64 + i * 16 + r16) * 32 + kq * 8];
#pragma unroll
    for (int j = 0; j < 4; ++j)
      bfr[j] = *(const bf16x8*)&Bs[(wc * 64 + j * 16 + r16) * 32 + kq * 8];
#pragma unroll
    for (int i = 0; i < 4; ++i)
#pragma unroll
      for (int j = 0; j < 4; ++j)
        acc[i][j] = __builtin_amdgcn_mfma_f32_16x16x32_bf16(af[i], bfr[j], acc[i][j], 0, 0, 0);
    __syncthreads();
  }
  float* out = PART + (size_t)s * 1024 * ldc;
#pragma unroll
  for (int i = 0; i < 4; ++i) {
    int row = bm + wr * 64 + i * 16 + kq * 4;
#pragma unroll
    for (int j = 0; j < 4; ++j) {
      int col = bn + wc * 64 + j * 16 + r16;
      if (col >= 1600) continue;
#pragma unroll
      for (int r = 0; r < 4; ++r)
        out[(size_t)(row + r) * ldc + col] = acc[i][j][r];
    }
  }
}

// reduce 8 K-slice partials + bias + relu -> ZB bf16 [1024][1664], pad cols zeroed
__global__ void zred(const float* __restrict__ PART, const float* __restrict__ bias,
                     unsigned short* __restrict__ ZB) {
  int idx = blockIdx.x * blockDim.x + threadIdx.x;
  if (idx >= 1024 * 1664) return;
  int r = idx / 1664, c = idx - r * 1664;
  if (c >= 1600) { ZB[idx] = 0; return; }
  float s = 0.f;
#pragma unroll
  for (int k = 0; k < 8; ++k) s += PART[(size_t)k * 1024 * 1664 + idx];
  s += bias[c];
  ZB[idx] = f2b(s > 0.f ? s : 0.f);
}

// ---------------- GAT pieces ----------------
__global__ void gat_scores_bf(const unsigned short* __restrict__ hlin,
                              const float* __restrict__ a_s, const float* __restrict__ a_d,
                              float* __restrict__ als, float* __restrict__ ald,
                              int H, int C, int tot) {
  int idx = blockIdx.x * blockDim.x + threadIdx.x;
  if (idx >= tot) return;
  int n = idx / H, h = idx - n * H;
  const unsigned short* base = hlin + (size_t)n * H * C + (size_t)h * C;
  const float* as = a_s + h * C;
  const float* ad = a_d + h * C;
  float ss = 0.f, sd = 0.f;
  for (int c = 0; c < C; c += 8) {
    ushort8 v = *(const ushort8*)(base + c);
#pragma unroll
    for (int t = 0; t < 8; ++t) {
      float f = b2f(v[t]);
      ss = fmaf(f, as[c + t], ss);
      sd = fmaf(f, ad[c + t], sd);
    }
  }
  als[idx] = ss;
  ald[idx] = sd;
}

// fused attention: p = exp(leaky_relu(als[src]+ald[dst])), sb[dst] += p
// (no max-subtraction: alpha = p/sum is mathematically identical, |e| << 88)
template <int H>
__global__ void edge_attn(const int* __restrict__ ei, const float* __restrict__ als,
                          const float* __restrict__ ald, float* __restrict__ eb,
                          float* __restrict__ sb) {
  int e = blockIdx.x * blockDim.x + threadIdx.x;
  if (e >= ETOT) return;
  int src, dst;
  if (e < E0) { src = ei[e]; dst = ei[E0 + e]; } else { src = dst = e - E0; }
  if (H == 8) {
    float4 s0 = *(const float4*)(als + src * 8);
    float4 s1 = *(const float4*)(als + src * 8 + 4);
    float4 d0 = *(const float4*)(ald + dst * 8);
    float4 d1 = *(const float4*)(ald + dst * 8 + 4);
    float ev[8] = {s0.x + d0.x, s0.y + d0.y, s0.z + d0.z, s0.w + d0.w,
                   s1.x + d1.x, s1.y + d1.y, s1.z + d1.z, s1.w + d1.w};
#pragma unroll
    for (int h = 0; h < 8; ++h) {
      float v = ev[h];
      v = (v >= 0.f) ? v : 0.2f * v;
      float p = __expf(v);
      eb[(size_t)e * 8 + h] = p;
      atomicAdd(&sb[dst * 8 + h], p);
    }
  } else {
    float v = als[src] + ald[dst];
    v = (v >= 0.f) ? v : 0.2f * v;
    float p = __expf(v);
    eb[e] = p;
    atomicAdd(&sb[dst], p);
  }
}

// vectorized aggregate: thread = (node, 8-channel chunk); one edge loop, ushort8 gather
template <int F, int C>
__global__ __launch_bounds__(256) void gat_agg_v2(
    const int* __restrict__ rowptr, const int* __restrict__ csr,
    const int* __restrict__ ei, const float* __restrict__ eb,
    const float* __restrict__ sb, const unsigned short* __restrict__ hlin,
    const float* __restrict__ bias, unsigned short* __restrict__ out) {
  constexpr int H = F / C;
  constexpr int CPN = F / 8;
  int gidx = blockIdx.x * 256 + threadIdx.x;
  if (gidx >= NN * CPN) return;
  int node = gidx / CPN;
  int c0 = (gidx - node * CPN) * 8;
  int h = c0 / C;
  float inv_s = 1.f / sb[node * H + h];
  float acc[8] = {0.f, 0.f, 0.f, 0.f, 0.f, 0.f, 0.f, 0.f};
  int start = rowptr[node], end = rowptr[node + 1];
  for (int k = start; k < end; ++k) {
    int eid = csr[k];
    int src = (eid < E0) ? ei[eid] : (eid - E0);
    float p = eb[(size_t)eid * H + h];
    ushort8 hv = *(const ushort8*)(hlin + (size_t)src * F + c0);
#pragma unroll
    for (int t = 0; t < 8; ++t) acc[t] = fmaf(p, b2f(hv[t]), acc[t]);
  }
  ushort8 o;
#pragma unroll
  for (int t = 0; t < 8; ++t) {
    float val = acc[t] * inv_s + bias[c0 + t];
    o[t] = f2b(val > 0.f ? val : 0.f);
  }
  *(ushort8*)(out + (size_t)node * F + c0) = o;
}

__global__ void pool_scatter_bf(const unsigned short* __restrict__ h,
                                const int* __restrict__ batch, float* xg, int F, int tot) {
  int idx = blockIdx.x * blockDim.x + threadIdx.x;
  if (idx >= tot) return;
  int n = idx / F, f = idx - n * F;
  atomicMaxF(&xg[batch[n] * F + f], b2f(h[idx]));
}

__global__ void rownorm(const float* __restrict__ in, float* __restrict__ outp) {
  int r = blockIdx.x, lane = threadIdx.x;
  float v = in[r * 64 + lane];
  float ss = v * v;
#pragma unroll
  for (int off = 1; off < 64; off <<= 1) ss += __shfl_xor(ss, off);
  float nrm = fmaxf(sqrtf(ss), 1e-12f);
  outp[r * 64 + lane] = v / nrm;
}

__global__ __launch_bounds__(256) void freq_k(const float* __restrict__ dn,
                                              const float* __restrict__ sn,
                                              float* __restrict__ C, int M, int N) {
  __shared__ float As[16][64];
  __shared__ float Bs[16][65];
  int tid = threadIdx.x;
  int tx = tid & 15, ty = tid >> 4;
  int bi = blockIdx.y * 16, bj = blockIdx.x * 16;
#pragma unroll
  for (int t = 0; t < 4; ++t) {
    int idx = tid * 4 + t;
    int r = idx >> 6, c = idx & 63;
    As[r][c] = (bi + r < M) ? dn[(bi + r) * 64 + c] : 0.f;
    Bs[r][c] = (bj + r < N) ? sn[(bj + r) * 64 + c] : 0.f;
  }
  __syncthreads();
  float acc = 0.f;
#pragma unroll
  for (int k = 0; k < 64; ++k) acc = fmaf(As[ty][k], Bs[tx][k], acc);
  if (bi + ty < M && bj + tx < N) C[(size_t)(bi + ty) * N + (bj + tx)] = 5.f * acc;
}

// ---------------- launch ----------------
extern "C" void kernel_launch(void* const* d_in, const int* in_sizes, int n_in,
                              void* d_out, int out_size, void* d_ws, size_t ws_size,
                              hipStream_t stream) {
  const float* x = (const float*)d_in[0];
  const int* ei = (const int*)d_in[1];
  const int* batch = (const int*)d_in[2];
  const float* w = (const float*)d_in[3];
  const float* z = (const float*)d_in[4];
  const float* v = (const float*)d_in[5];
  const float* side = (const float*)d_in[6];
  const float* gW[4] = {(const float*)d_in[7], (const float*)d_in[11],
                        (const float*)d_in[15], (const float*)d_in[19]};
  const float* gas[4] = {(const float*)d_in[8], (const float*)d_in[12],
                         (const float*)d_in[16], (const float*)d_in[20]};
  const float* gad[4] = {(const float*)d_in[9], (const float*)d_in[13],
                         (const float*)d_in[17], (const float*)d_in[21]};
  const float* gb[4] = {(const float*)d_in[10], (const float*)d_in[14],
                        (const float*)d_in[18], (const float*)d_in[22]};
  const float* x5_W = (const float*)d_in[23]; const float* x5_b = (const float*)d_in[24];
  const float* x6_W = (const float*)d_in[25]; const float* x6_b = (const float*)d_in[26];
  const float* w1_W = (const float*)d_in[27]; const float* w1_b = (const float*)d_in[28];
  const float* w2_W = (const float*)d_in[29]; const float* w2_b = (const float*)d_in[30];
  const float* z1_W = (const float*)d_in[31]; const float* z1_b = (const float*)d_in[32];
  const float* z2_W = (const float*)d_in[33]; const float* z2_b = (const float*)d_in[34];
  const float* v1_W = (const float*)d_in[35]; const float* v1_b = (const float*)d_in[36];
  const float* v2_W = (const float*)d_in[37]; const float* v2_b = (const float*)d_in[38];
  const float* agg_W = (const float*)d_in[39]; const float* agg_b = (const float*)d_in[40];
  const float* col_W = (const float*)d_in[41]; const float* col_b = (const float*)d_in[42];
  const float* s1_W = (const float*)d_in[43]; const float* s1_b = (const float*)d_in[44];
  const float* s2_W = (const float*)d_in[45]; const float* s2_b = (const float*)d_in[46];

  char* wsb = (char*)d_ws;
  size_t off = 0;
  auto alloc = [&](size_t bytes) {
    void* p = wsb + off;
    off = (off + bytes + 255) & ~(size_t)255;
    return p;
  };
  unsigned short* HLIN = (unsigned short*)alloc((size_t)NN * 1024 * 2);  // aliased as PART later
  unsigned short* XB = (unsigned short*)alloc((size_t)NN * 1024 * 2);
  unsigned short* WTZ = (unsigned short*)alloc((size_t)1664 * 19136 * 2);
  unsigned short* ZA = (unsigned short*)alloc((size_t)1024 * 19136 * 2);
  unsigned short* WT1 = (unsigned short*)alloc((size_t)768 * 128 * 2);
  unsigned short* WT2 = (unsigned short*)alloc((size_t)1024 * 768 * 2);
  unsigned short* WT3 = (unsigned short*)alloc((size_t)1024 * 1024 * 2);
  unsigned short* WT4 = (unsigned short*)alloc((size_t)128 * 1024 * 2);
  unsigned short* WTW1 = (unsigned short*)alloc((size_t)768 * 768 * 2);
  unsigned short* WTW2 = (unsigned short*)alloc((size_t)128 * 768 * 2);
  unsigned short* WTZ2 = (unsigned short*)alloc((size_t)128 * 1664 * 2);
  unsigned short* WTV1 = (unsigned short*)alloc((size_t)256 * 1024 * 2);
  unsigned short* WTV2 = (unsigned short*)alloc((size_t)128 * 256 * 2);
  unsigned short* WTX5 = (unsigned short*)alloc((size_t)128 * 128 * 2);
  unsigned short* WTX6 = (unsigned short*)alloc((size_t)128 * 64 * 2);
  unsigned short* WTAGG = (unsigned short*)alloc((size_t)128 * 192 * 2);
  unsigned short* WTCOL = (unsigned short*)alloc((size_t)128 * 128 * 2);
  unsigned short* WTS1 = (unsigned short*)alloc((size_t)128 * 1056 * 2);
  unsigned short* WTS2 = (unsigned short*)alloc((size_t)128 * 64 * 2);
  unsigned short* WB = (unsigned short*)alloc((size_t)1024 * 768 * 2);
  unsigned short* VB = (unsigned short*)alloc((size_t)1024 * 1024 * 2);
  unsigned short* SIDEB = (unsigned short*)alloc((size_t)1024 * 1056 * 2);
  unsigned short* XGB = (unsigned short*)alloc((size_t)1024 * 128 * 2);
  unsigned short* ZB = (unsigned short*)alloc((size_t)1024 * 1664 * 2);
  unsigned short* X5O = (unsigned short*)alloc((size_t)1024 * 128 * 2);
  unsigned short* WMID = (unsigned short*)alloc((size_t)1024 * 768 * 2);
  unsigned short* VMID = (unsigned short*)alloc((size_t)1024 * 256 * 2);
  unsigned short* SEMID = (unsigned short*)alloc((size_t)1024 * 128 * 2);
  unsigned short* CAT192 = (unsigned short*)alloc((size_t)1024 * 192 * 2);
  unsigned short* CAT128 = (unsigned short*)alloc((size_t)1024 * 128 * 2);
  float* EB = (float*)alloc((size_t)ETOT * 8 * 4);
  float* ALS = (float*)alloc((size_t)NN * 8 * 4);
  float* ALD = (float*)alloc((size_t)NN * 8 * 4);
  float* SB = (float*)alloc((size_t)NN * 8 * 4);
  float* XG = (float*)alloc((size_t)NB * 128 * 4);
  float* DRUG = (float*)alloc((size_t)NB * 64 * 4);
  float* SE = (float*)alloc((size_t)1024 * 64 * 4);
  int* DEG = (int*)alloc((size_t)NN * 4);
  int* ROWPTR = (int*)alloc((size_t)(NN + 1) * 4);
  int* CURSOR = (int*)alloc((size_t)NN * 4);
  int* CSR = (int*)alloc((size_t)ETOT * 4);
  float* PART = (float*)HLIN;  // 8*1024*1664*4 = 54.5MB <= 64MB

  // CSR build
  hipLaunchKernelGGL(fill_i32, dim3((NN + 255) / 256), dim3(256), 0, stream, DEG, 0, NN);
  hipLaunchKernelGGL(count_deg, dim3((ETOT + 255) / 256), dim3(256), 0, stream, ei, DEG);
  hipLaunchKernelGGL(scan_deg, dim3(1), dim3(1024), 0, stream, DEG, ROWPTR);
  hipLaunchKernelGGL(copy_i32, dim3((NN + 255) / 256), dim3(256), 0, stream, ROWPTR, CURSOR, NN);
  hipLaunchKernelGGL(fill_csr, dim3((ETOT + 255) / 256), dim3(256), 0, stream, ei, CURSOR, CSR);

  // weight transposes (WT[Npad][Kp], zero-padded)
  auto launch_tw = [&](const float* W, unsigned short* WT, int K, int N, int Kp, int Npad) {
    dim3 g((Npad + 31) / 32, (Kp + 31) / 32);
    hipLaunchKernelGGL(transpose_w, g, dim3(256), 0, stream, W, WT, K, N, Kp, Npad);
  };
  launch_tw(gW[0], WT1, 109, 768, 128, 768);
  launch_tw(gW[1], WT2, 768, 1024, 768, 1024);
  launch_tw(gW[2], WT3, 1024, 1024, 1024, 1024);
  launch_tw(gW[3], WT4, 1024, 128, 1024, 128);
  launch_tw(z1_W, WTZ, 19127, 1600, 19136, 1664);
  launch_tw(w1_W, WTW1, 750, 750, 768, 768);
  launch_tw(w2_W, WTW2, 750, 64, 768, 128);
  launch_tw(z2_W, WTZ2, 1600, 64, 1664, 128);
  launch_tw(v1_W, WTV1, 1024, 256, 1024, 256);
  launch_tw(v2_W, WTV2, 256, 64, 256, 128);
  launch_tw(x5_W, WTX5, 128, 64, 128, 128);
  launch_tw(x6_W, WTX6, 64, 64, 64, 128);
  launch_tw(agg_W, WTAGG, 192, 64, 192, 128);
  launch_tw(col_W, WTCOL, 128, 64, 128, 128);
  launch_tw(s1_W, WTS1, 1050, 64, 1056, 128);
  launch_tw(s2_W, WTS2, 64, 64, 64, 128);

  // input conversions
  auto launch_conv = [&](const float* in, unsigned short* out, int rowsOut, int Rreal, int C, int Cp) {
    size_t tot = (size_t)rowsOut * Cp;
    hipLaunchKernelGGL(conv_pad, dim3((unsigned)((tot + 255) / 256)), dim3(256), 0, stream,
                       in, out, rowsOut, Rreal, C, Cp);
  };
  launch_conv(x, XB, NN, NN, 109, 128);
  launch_conv(z, ZA, NB, NB, 19127, 19136);
  launch_conv(w, WB, 1024, 1024, 750, 768);
  launch_conv(v, VB, 1024, 1024, 1024, 1024);
  launch_conv(side, SIDEB, 1024, 994, 1050, 1056);

  auto mm = [&](int act, int obf, const unsigned short* A, const unsigned short* BT,
                const float* bias, void* C, int M, int Npad, int Nreal, int K,
                int lda, int ldb, int ldc, int zpad) {
    int gx = Npad / 128;
    int nwg = gx * (M / 128);
    switch (act * 2 + obf) {
      case 0: hipLaunchKernelGGL((gemm_mfma<0,0>), dim3(nwg), dim3(256), 0, stream, A, BT, bias, C, Nreal, K, lda, ldb, ldc, gx, zpad); break;
      case 1: hipLaunchKernelGGL((gemm_mfma<0,1>), dim3(nwg), dim3(256), 0, stream, A, BT, bias, C, Nreal, K, lda, ldb, ldc, gx, zpad); break;
      case 2: hipLaunchKernelGGL((gemm_mfma<1,0>), dim3(nwg), dim3(256), 0, stream, A, BT, bias, C, Nreal, K, lda, ldb, ldc, gx, zpad); break;
      case 3: hipLaunchKernelGGL((gemm_mfma<1,1>), dim3(nwg), dim3(256), 0, stream, A, BT, bias, C, Nreal, K, lda, ldb, ldc, gx, zpad); break;
      case 4: hipLaunchKernelGGL((gemm_mfma<2,0>), dim3(nwg), dim3(256), 0, stream, A, BT, bias, C, Nreal, K, lda, ldb, ldc, gx, zpad); break;
      case 6: hipLaunchKernelGGL((gemm_mfma<3,0>), dim3(nwg), dim3(256), 0, stream, A, BT, bias, C, Nreal, K, lda, ldb, ldc, gx, zpad); break;
      default: break;
    }
  };

  // GAT layers
  const int Hs[4] = {8, 8, 8, 1};
  const int Cs[4] = {96, 128, 128, 128};
  const int Kp[4] = {128, 768, 1024, 1024};
  const unsigned short* WTs[4] = {WT1, WT2, WT3, WT4};
  for (int l = 0; l < 4; ++l) {
    int H = Hs[l], C = Cs[l], F = H * C;
    mm(0, 1, XB, WTs[l], nullptr, HLIN, NN, F, F, Kp[l], Kp[l], Kp[l], F, 0);
    int totNH = NN * H;
    hipLaunchKernelGGL(gat_scores_bf, dim3((totNH + 255) / 256), dim3(256), 0, stream,
                       HLIN, gas[l], gad[l], ALS, ALD, H, C, totNH);
    hipLaunchKernelGGL(fill_f32, dim3((totNH + 255) / 256), dim3(256), 0, stream, SB, 0.f, totNH);
    if (H == 8)
      hipLaunchKernelGGL((edge_attn<8>), dim3((ETOT + 255) / 256), dim3(256), 0, stream, ei, ALS, ALD, EB, SB);
    else
      hipLaunchKernelGGL((edge_attn<1>), dim3((ETOT + 255) / 256), dim3(256), 0, stream, ei, ALS, ALD, EB, SB);
    if (l == 0)
      hipLaunchKernelGGL((gat_agg_v2<768, 96>), dim3(NN * 96 / 256), dim3(256), 0, stream,
                         ROWPTR, CSR, ei, EB, SB, HLIN, gb[l], XB);
    else if (l == 3)
      hipLaunchKernelGGL((gat_agg_v2<128, 128>), dim3(NN * 16 / 256), dim3(256), 0, stream,
                         ROWPTR, CSR, ei, EB, SB, HLIN, gb[l], XB);
    else
      hipLaunchKernelGGL((gat_agg_v2<1024, 128>), dim3(NN * 128 / 256), dim3(256), 0, stream,
                         ROWPTR, CSR, ei, EB, SB, HLIN, gb[l], XB);
  }

  // global max pool -> XG f32 -> XGB bf16
  hipLaunchKernelGGL(fill_f32, dim3((NB * 128 + 255) / 256), dim3(256), 0, stream, XG, -FLT_MAX, NB * 128);
  hipLaunchKernelGGL(pool_scatter_bf, dim3((NN * 128 + 255) / 256), dim3(256), 0, stream, XB, batch, XG, 128, NN * 128);
  launch_conv(XG, XGB, 1024, 1024, 128, 128);

  // z1 split-K + reduce -> ZB bf16
  hipLaunchKernelGGL(gemm_mfma_sk, dim3(832), dim3(256), 0, stream, ZA, WTZ, PART, 19136, 19136, 1664);
  hipLaunchKernelGGL(zred, dim3((1024 * 1664 + 255) / 256), dim3(256), 0, stream, PART, z1_b, ZB);

  // tail chains (all MFMA bf16)
  mm(1, 1, XGB, WTX5, x5_b, X5O, 1024, 128, 64, 128, 128, 128, 128, 1);       // x5
  mm(1, 1, X5O, WTX6, x6_b, CAT192 + 0, 1024, 128, 64, 64, 128, 64, 192, 0);  // x6
  mm(1, 1, WB, WTW1, w1_b, WMID, 1024, 768, 750, 768, 768, 768, 768, 1);      // w1
  mm(1, 1, WMID, WTW2, w2_b, CAT192 + 64, 1024, 128, 64, 768, 768, 768, 192, 0);  // w2
  mm(1, 1, ZB, WTZ2, z2_b, CAT192 + 128, 1024, 128, 64, 1664, 1664, 1664, 192, 0); // z2
  mm(1, 1, VB, WTV1, v1_b, VMID, 1024, 256, 256, 1024, 1024, 1024, 256, 0);   // v1
  mm(1, 1, VMID, WTV2, v2_b, CAT128 + 64, 1024, 128, 64, 256, 256, 256, 128, 0);   // v2
  mm(0, 1, CAT192, WTAGG, agg_b, CAT128 + 0, 1024, 128, 64, 192, 192, 192, 128, 0); // agg
  mm(3, 0, CAT128, WTCOL, col_b, DRUG, 1024, 128, 64, 128, 128, 128, 64, 0);  // col: |tanh|
  mm(1, 1, SIDEB, WTS1, s1_b, SEMID, 1024, 128, 64, 1056, 1056, 1056, 128, 1); // s1
  mm(2, 0, SEMID, WTS2, s2_b, SE, 1024, 128, 64, 64, 128, 64, 64, 0);         // s2: tanh

  // normalize + similarity
  float* outp = (float*)d_out;
  float* DN = outp + (size_t)NB * NSIDE;
  float* SN = DN + (size_t)NB * 64;
  hipLaunchKernelGGL(rownorm, dim3(NB), dim3(64), 0, stream, DRUG, DN);
  hipLaunchKernelGGL(rownorm, dim3(NSIDE), dim3(64), 0, stream, SE, SN);
  hipLaunchKernelGGL(freq_k, dim3((NSIDE + 15) / 16, (NB + 15) / 16), dim3(256), 0, stream,
                     DN, SN, outp, NB, NSIDE);
}